// Round 1
// baseline (685.163 us; speedup 1.0000x reference)
//
#include <hip/hip_runtime.h>
#include <hip/hip_bf16.h>

// Problem constants
// B=1, S=8, N=512, DV=256, DM=64, INNER=256, H=8, WS=3, DH=32
#define S_ 8
#define N_ 512
#define DV_ 256
#define DM_ 64
#define INNER_ 256
#define H_ 8
#define WS_ 3
#define DH_ 32

__device__ __forceinline__ float clip5(float x) {
    return fminf(5.0f, fmaxf(-5.0f, x));
}

// ---------------------------------------------------------------------------
// Kernel 1: outer metadata attention + top-3 window selection (tiny, 1 block)
// ---------------------------------------------------------------------------
__global__ __launch_bounds__(256) void outer_topk(
    const float* __restrict__ metadata,      // [8,512,64]
    const float* __restrict__ w_meta_outer,  // [64,512]
    int* __restrict__ topidx)                // [8,3]
{
    __shared__ float mm[S_][DM_];
    __shared__ float qmS[S_][INNER_];
    __shared__ float kmS[S_][INNER_];
    __shared__ float dots[S_][S_];
    int tid = threadIdx.x;

    // meta_mean over N
    for (int i = tid; i < S_ * DM_; i += 256) {
        int s = i >> 6, d = i & 63;
        float acc = 0.0f;
        for (int n = 0; n < N_; n++) acc += metadata[(s * N_ + n) * DM_ + d];
        mm[s][d] = acc * (1.0f / (float)N_);
    }
    __syncthreads();

    // meta_mean @ w_meta_outer -> qm | km, clipped
    for (int i = tid; i < S_ * 2 * INNER_; i += 256) {
        int s = i >> 9, c = i & 511;
        float acc = 0.0f;
        for (int k = 0; k < DM_; k++) acc += mm[s][k] * w_meta_outer[k * 512 + c];
        acc = clip5(acc);
        if (c < INNER_) qmS[s][c] = acc; else kmS[s][c - INNER_] = acc;
    }
    __syncthreads();

    // dots = qm km^T * INNER^-0.5
    if (tid < 64) {
        int qi = tid >> 3, ki = tid & 7;
        float acc = 0.0f;
        for (int j = 0; j < INNER_; j++) acc += qmS[qi][j] * kmS[ki][j];
        dots[qi][ki] = acc * 0.0625f;  // 1/sqrt(256)
    }
    __syncthreads();

    // softmax + 2I, stable top-3 (strict > => lowest index on ties)
    if (tid < S_) {
        int r = tid;
        float mx = -1e30f;
        for (int k = 0; k < S_; k++) mx = fmaxf(mx, dots[r][k]);
        float e[S_], sum = 0.0f;
        for (int k = 0; k < S_; k++) { e[k] = __expf(dots[r][k] - mx); sum += e[k]; }
        float vals[S_];
        for (int k = 0; k < S_; k++) vals[k] = e[k] / sum + (k == r ? 2.0f : 0.0f);
        bool used[S_];
        for (int k = 0; k < S_; k++) used[k] = false;
        for (int w = 0; w < WS_; w++) {
            float best = -1e30f; int bi = 0;
            for (int k = 0; k < S_; k++) {
                if (!used[k] && vals[k] > best) { best = vals[k]; bi = k; }
            }
            used[bi] = true;
            topidx[r * WS_ + w] = bi;
        }
    }
}

// ---------------------------------------------------------------------------
// Kernel 2a: values -> QP (clipped), KP (clipped), V for all 4096 tokens
// grid 128 blocks x 256 threads, 32 tokens/block, thread = output column
// ---------------------------------------------------------------------------
__global__ __launch_bounds__(256) void proj_qkv(
    const float* __restrict__ values,  // [4096,256]
    const float* __restrict__ w_qkv,   // [256,768]
    float* __restrict__ QP, float* __restrict__ KP, float* __restrict__ V)
{
    __shared__ float4 Xs[32 * 64];  // 32 tokens x 256 ch
    int t0 = blockIdx.x * 32;
    int tid = threadIdx.x;
    const float4* v4 = (const float4*)(values + (size_t)t0 * DV_);
    for (int i = tid; i < 32 * 64; i += 256) Xs[i] = v4[i];
    __syncthreads();

    int c = tid;
    float aq[32], ak[32], av[32];
#pragma unroll
    for (int t = 0; t < 32; t++) { aq[t] = 0.f; ak[t] = 0.f; av[t] = 0.f; }

    for (int k0 = 0; k0 < DV_; k0 += 4) {
        float wq[4], wk[4], wv[4];
#pragma unroll
        for (int j = 0; j < 4; j++) {
            const float* wr = w_qkv + (size_t)(k0 + j) * 768 + c;
            wq[j] = wr[0]; wk[j] = wr[256]; wv[j] = wr[512];
        }
#pragma unroll
        for (int t = 0; t < 32; t++) {
            float4 x = Xs[t * 64 + (k0 >> 2)];
            aq[t] += x.x * wq[0] + x.y * wq[1] + x.z * wq[2] + x.w * wq[3];
            ak[t] += x.x * wk[0] + x.y * wk[1] + x.z * wk[2] + x.w * wk[3];
            av[t] += x.x * wv[0] + x.y * wv[1] + x.z * wv[2] + x.w * wv[3];
        }
    }
#pragma unroll
    for (int t = 0; t < 32; t++) {
        size_t o = (size_t)(t0 + t) * DV_ + c;
        QP[o] = clip5(aq[t]);
        KP[o] = clip5(ak[t]);
        V[o]  = av[t];
    }
}

// ---------------------------------------------------------------------------
// Kernel 2b: metadata -> QM (clipped), KM (clipped)
// ---------------------------------------------------------------------------
__global__ __launch_bounds__(256) void proj_meta(
    const float* __restrict__ metadata,      // [4096,64]
    const float* __restrict__ w_meta_inner,  // [64,512]
    float* __restrict__ QM, float* __restrict__ KM)
{
    __shared__ float4 Xs[32 * 16];  // 32 tokens x 64 ch
    int t0 = blockIdx.x * 32;
    int tid = threadIdx.x;
    const float4* m4 = (const float4*)(metadata + (size_t)t0 * DM_);
    for (int i = tid; i < 32 * 16; i += 256) Xs[i] = m4[i];
    __syncthreads();

    int c = tid;
    float aq[32], ak[32];
#pragma unroll
    for (int t = 0; t < 32; t++) { aq[t] = 0.f; ak[t] = 0.f; }

    for (int k0 = 0; k0 < DM_; k0 += 4) {
        float wq[4], wk[4];
#pragma unroll
        for (int j = 0; j < 4; j++) {
            const float* wr = w_meta_inner + (size_t)(k0 + j) * 512 + c;
            wq[j] = wr[0]; wk[j] = wr[256];
        }
#pragma unroll
        for (int t = 0; t < 32; t++) {
            float4 x = Xs[t * 16 + (k0 >> 2)];
            aq[t] += x.x * wq[0] + x.y * wq[1] + x.z * wq[2] + x.w * wq[3];
            ak[t] += x.x * wk[0] + x.y * wk[1] + x.z * wk[2] + x.w * wk[3];
        }
    }
#pragma unroll
    for (int t = 0; t < 32; t++) {
        size_t o = (size_t)(t0 + t) * INNER_ + c;
        QM[o] = clip5(aq[t]);
        KM[o] = clip5(ak[t]);
    }
}

// ---------------------------------------------------------------------------
// Kernel 3: flash attention partial per (s, h, qtile, window)
// grid (8, 8, 8*3), 64 threads; 1 query-head per lane; 32-key LDS tiles
// ---------------------------------------------------------------------------
__global__ __launch_bounds__(64) void attn_partial(
    const int* __restrict__ topidx,
    const float* __restrict__ QP, const float* __restrict__ KP,
    const float* __restrict__ V,  const float* __restrict__ QM,
    const float* __restrict__ KM,
    float* __restrict__ PO, float* __restrict__ PM, float* __restrict__ PL)
{
    int s  = blockIdx.x;
    int h  = blockIdx.y;
    int qt = blockIdx.z & 7;
    int w  = blockIdx.z >> 3;  // 0..2
    int tid = threadIdx.x;
    int q = qt * 64 + tid;

    int src0 = topidx[s * WS_ + 0];
    int srcw = topidx[s * WS_ + w];

    const float scale = 0.17677669529663687f;  // 1/sqrt(32)

    // load q vectors (scale folded in)
    float qp[32], qm[32];
    {
        const float4* qp4 = (const float4*)(QP + ((size_t)(src0 * N_ + q) * DV_ + h * DH_));
        const float4* qm4 = (const float4*)(QM + ((size_t)(src0 * N_ + q) * INNER_ + h * DH_));
#pragma unroll
        for (int j = 0; j < 8; j++) {
            float4 a = qp4[j];
            qp[4 * j + 0] = a.x * scale; qp[4 * j + 1] = a.y * scale;
            qp[4 * j + 2] = a.z * scale; qp[4 * j + 3] = a.w * scale;
            float4 b = qm4[j];
            qm[4 * j + 0] = b.x * scale; qm[4 * j + 1] = b.y * scale;
            qm[4 * j + 2] = b.z * scale; qm[4 * j + 3] = b.w * scale;
        }
    }

    float o[32];
#pragma unroll
    for (int j = 0; j < 32; j++) o[j] = 0.0f;
    float m = -1e30f, l = 0.0f;

    __shared__ float4 kps[32 * 8];
    __shared__ float4 kms[32 * 8];
    __shared__ float4 vs[32 * 8];

    const float4* KP4 = (const float4*)KP;
    const float4* KM4 = (const float4*)KM;
    const float4* V4  = (const float4*)V;

    for (int kt = 0; kt < 16; kt++) {
        __syncthreads();
        int kbase = srcw * N_ + kt * 32;
        for (int i = tid; i < 256; i += 64) {
            int key = i >> 3, c4 = i & 7;
            size_t g = (size_t)(kbase + key) * 64 + h * 8 + c4;
            kps[i] = KP4[g];
            kms[i] = KM4[g];
            vs[i]  = V4[g];
        }
        __syncthreads();

        for (int key = 0; key < 32; key++) {
            float sc = 0.0f;
#pragma unroll
            for (int j = 0; j < 8; j++) {
                float4 kk = kps[key * 8 + j];
                sc += qp[4 * j + 0] * kk.x + qp[4 * j + 1] * kk.y
                    + qp[4 * j + 2] * kk.z + qp[4 * j + 3] * kk.w;
                float4 km_ = kms[key * 8 + j];
                sc += qm[4 * j + 0] * km_.x + qm[4 * j + 1] * km_.y
                    + qm[4 * j + 2] * km_.z + qm[4 * j + 3] * km_.w;
            }
            float nm = fmaxf(m, sc);
            float corr = __expf(m - nm);
            float p = __expf(sc - nm);
            l = l * corr + p;
            m = nm;
#pragma unroll
            for (int j = 0; j < 8; j++) {
                float4 vv = vs[key * 8 + j];
                o[4 * j + 0] = o[4 * j + 0] * corr + p * vv.x;
                o[4 * j + 1] = o[4 * j + 1] * corr + p * vv.y;
                o[4 * j + 2] = o[4 * j + 2] * corr + p * vv.z;
                o[4 * j + 3] = o[4 * j + 3] * corr + p * vv.w;
            }
        }
    }

    // write partials: layout [w][s][h][q]
    size_t base = (size_t)((w * 64 + s * 8 + h) * N_ + q);
    PM[base] = m;
    PL[base] = l;
    float4* po4 = (float4*)(PO + base * 32);
#pragma unroll
    for (int j = 0; j < 8; j++) {
        po4[j] = make_float4(o[4 * j + 0], o[4 * j + 1], o[4 * j + 2], o[4 * j + 3]);
    }
}

// ---------------------------------------------------------------------------
// Kernel 3b: combine 3 window partials -> AO [s][q][inner]
// ---------------------------------------------------------------------------
__global__ __launch_bounds__(256) void attn_combine(
    const float* __restrict__ PO, const float* __restrict__ PM,
    const float* __restrict__ PL, float* __restrict__ AO)
{
    int i = blockIdx.x * 256 + threadIdx.x;  // (s,h,q) flattened: 32768
    int s = i >> 12;
    int h = (i >> 9) & 7;
    int q = i & 511;

    float m0 = PM[i], m1 = PM[32768 + i], m2 = PM[65536 + i];
    float M = fmaxf(m0, fmaxf(m1, m2));
    float c0 = __expf(m0 - M);
    float c1 = __expf(m1 - M);
    float c2 = __expf(m2 - M);
    float L = PL[i] * c0 + PL[32768 + i] * c1 + PL[65536 + i] * c2;
    float inv = 1.0f / L;
    c0 *= inv; c1 *= inv; c2 *= inv;

    const float4* p0 = (const float4*)(PO + (size_t)i * 32);
    const float4* p1 = (const float4*)(PO + (size_t)(32768 + i) * 32);
    const float4* p2 = (const float4*)(PO + (size_t)(65536 + i) * 32);
    float4* ao = (float4*)(AO + ((size_t)(s * N_ + q) * INNER_ + h * DH_));
#pragma unroll
    for (int j = 0; j < 8; j++) {
        float4 a = p0[j], b = p1[j], c = p2[j];
        ao[j] = make_float4(a.x * c0 + b.x * c1 + c.x * c2,
                            a.y * c0 + b.y * c1 + c.y * c2,
                            a.z * c0 + b.z * c1 + c.z * c2,
                            a.w * c0 + b.w * c1 + c.w * c2);
    }
}

// ---------------------------------------------------------------------------
// Kernel 4: output projection AO @ w_out + b_out -> out
// ---------------------------------------------------------------------------
__global__ __launch_bounds__(256) void out_proj(
    const float* __restrict__ AO,     // [4096,256]
    const float* __restrict__ w_out,  // [256,256]
    const float* __restrict__ b_out,  // [256]
    float* __restrict__ out)          // [4096,256]
{
    __shared__ float4 Xs[32 * 64];
    int t0 = blockIdx.x * 32;
    int tid = threadIdx.x;
    const float4* a4 = (const float4*)(AO + (size_t)t0 * INNER_);
    for (int i = tid; i < 32 * 64; i += 256) Xs[i] = a4[i];
    __syncthreads();

    int c = tid;
    float acc[32];
#pragma unroll
    for (int t = 0; t < 32; t++) acc[t] = 0.f;

    for (int k0 = 0; k0 < INNER_; k0 += 4) {
        float w0 = w_out[(size_t)(k0 + 0) * 256 + c];
        float w1 = w_out[(size_t)(k0 + 1) * 256 + c];
        float w2 = w_out[(size_t)(k0 + 2) * 256 + c];
        float w3 = w_out[(size_t)(k0 + 3) * 256 + c];
#pragma unroll
        for (int t = 0; t < 32; t++) {
            float4 x = Xs[t * 64 + (k0 >> 2)];
            acc[t] += x.x * w0 + x.y * w1 + x.z * w2 + x.w * w3;
        }
    }
    float b = b_out[c];
#pragma unroll
    for (int t = 0; t < 32; t++) {
        out[(size_t)(t0 + t) * 256 + c] = acc[t] + b;
    }
}

// ---------------------------------------------------------------------------
extern "C" void kernel_launch(void* const* d_in, const int* in_sizes, int n_in,
                              void* d_out, int out_size, void* d_ws, size_t ws_size,
                              hipStream_t stream) {
    const float* values       = (const float*)d_in[0];  // [1,8,512,256]
    const float* metadata     = (const float*)d_in[1];  // [1,8,512,64]
    const float* w_meta_outer = (const float*)d_in[2];  // [64,512]
    const float* w_qkv        = (const float*)d_in[3];  // [256,768]
    const float* w_meta_inner = (const float*)d_in[4];  // [64,512]
    const float* w_out        = (const float*)d_in[5];  // [256,256]
    const float* b_out        = (const float*)d_in[6];  // [256]
    float* out = (float*)d_out;

    int* topidx = (int*)d_ws;
    float* wsf = (float*)((char*)d_ws + 256);
    const size_t M1 = 1048576;  // 4096*256
    float* QP = wsf + 0 * M1;
    float* KP = wsf + 1 * M1;
    float* V  = wsf + 2 * M1;
    float* QM = wsf + 3 * M1;
    float* KM = wsf + 4 * M1;
    float* AO = wsf + 5 * M1;
    float* PO = wsf + 6 * M1;          // 3*8*8*512*32 = 3145728 floats
    float* PM = PO + 3145728;          // 98304 floats
    float* PL = PM + 98304;            // 98304 floats

    outer_topk<<<dim3(1), dim3(256), 0, stream>>>(metadata, w_meta_outer, topidx);
    proj_qkv<<<dim3(128), dim3(256), 0, stream>>>(values, w_qkv, QP, KP, V);
    proj_meta<<<dim3(128), dim3(256), 0, stream>>>(metadata, w_meta_inner, QM, KM);
    attn_partial<<<dim3(8, 8, 24), dim3(64), 0, stream>>>(topidx, QP, KP, V, QM, KM, PO, PM, PL);
    attn_combine<<<dim3(128), dim3(256), 0, stream>>>(PO, PM, PL, AO);
    out_proj<<<dim3(128), dim3(256), 0, stream>>>(AO, w_out, b_out, out);
}

// Round 2
// 331.292 us; speedup vs baseline: 2.0682x; 2.0682x over previous
//
#include <hip/hip_runtime.h>
#include <hip/hip_bf16.h>

// B=1, S=8, N=512, DV=256, DM=64, INNER=256, H=8, WS=3, DH=32
#define S_ 8
#define N_ 512
#define DV_ 256
#define DM_ 64
#define INNER_ 256
#define H_ 8
#define WS_ 3
#define DH_ 32

typedef __attribute__((ext_vector_type(8))) __bf16 bf16x8;
typedef __attribute__((ext_vector_type(4))) float f32x4;

__device__ __forceinline__ float clip5(float x) {
    return fminf(5.0f, fmaxf(-5.0f, x));
}
__device__ __forceinline__ unsigned short f2bf(float x) {
    __hip_bfloat16 h = __float2bfloat16(x);
    return *reinterpret_cast<unsigned short*>(&h);
}

// ---------------------------------------------------------------------------
// Kernel 1: outer metadata attention + top-3 window selection (tiny, 1 block)
// ---------------------------------------------------------------------------
__global__ __launch_bounds__(256) void outer_topk(
    const float* __restrict__ metadata,      // [8,512,64]
    const float* __restrict__ w_meta_outer,  // [64,512]
    int* __restrict__ topidx)                // [8,3]
{
    __shared__ float mm[S_][DM_];
    __shared__ float qmS[S_][INNER_];
    __shared__ float kmS[S_][INNER_];
    __shared__ float dots[S_][S_];
    int tid = threadIdx.x;

    for (int i = tid; i < S_ * DM_; i += 256) {
        int s = i >> 6, d = i & 63;
        float acc = 0.0f;
        for (int n = 0; n < N_; n++) acc += metadata[(s * N_ + n) * DM_ + d];
        mm[s][d] = acc * (1.0f / (float)N_);
    }
    __syncthreads();

    for (int i = tid; i < S_ * 2 * INNER_; i += 256) {
        int s = i >> 9, c = i & 511;
        float acc = 0.0f;
        for (int k = 0; k < DM_; k++) acc += mm[s][k] * w_meta_outer[k * 512 + c];
        acc = clip5(acc);
        if (c < INNER_) qmS[s][c] = acc; else kmS[s][c - INNER_] = acc;
    }
    __syncthreads();

    if (tid < 64) {
        int qi = tid >> 3, ki = tid & 7;
        float acc = 0.0f;
        for (int j = 0; j < INNER_; j++) acc += qmS[qi][j] * kmS[ki][j];
        dots[qi][ki] = acc * 0.0625f;  // 1/sqrt(256)
    }
    __syncthreads();

    if (tid < S_) {
        int r = tid;
        float mx = -1e30f;
        for (int k = 0; k < S_; k++) mx = fmaxf(mx, dots[r][k]);
        float e[S_], sum = 0.0f;
        for (int k = 0; k < S_; k++) { e[k] = __expf(dots[r][k] - mx); sum += e[k]; }
        float vals[S_];
        for (int k = 0; k < S_; k++) vals[k] = e[k] / sum + (k == r ? 2.0f : 0.0f);
        bool used[S_];
        for (int k = 0; k < S_; k++) used[k] = false;
        for (int w = 0; w < WS_; w++) {
            float best = -1e30f; int bi = 0;
            for (int k = 0; k < S_; k++) {
                if (!used[k] && vals[k] > best) { best = vals[k]; bi = k; }
            }
            used[bi] = true;
            topidx[r * WS_ + w] = bi;
        }
    }
}

// ---------------------------------------------------------------------------
// Kernel 2a: values -> Qc(qp half), Kc(kp half) clipped bf16; Vt transposed bf16
// Qc/Kc: [tok 4096][h 8][64]  (first 32 = projection half)
// Vt:    [s 8][h 8][dh 32][tok 512]
// ---------------------------------------------------------------------------
__global__ __launch_bounds__(256) void proj_qkv(
    const float* __restrict__ values,  // [4096,256]
    const float* __restrict__ w_qkv,   // [256,768]
    unsigned short* __restrict__ Qc,
    unsigned short* __restrict__ Kc,
    unsigned short* __restrict__ Vt)
{
    __shared__ float4 Xs[32 * 64];  // 32 tokens x 256 ch
    int t0 = blockIdx.x * 32;
    int tid = threadIdx.x;
    const float4* v4 = (const float4*)(values + (size_t)t0 * DV_);
    for (int i = tid; i < 32 * 64; i += 256) Xs[i] = v4[i];
    __syncthreads();

    int c = tid;
    float aq[32], ak[32], av[32];
#pragma unroll
    for (int t = 0; t < 32; t++) { aq[t] = 0.f; ak[t] = 0.f; av[t] = 0.f; }

    for (int k0 = 0; k0 < DV_; k0 += 4) {
        float wq[4], wk[4], wv[4];
#pragma unroll
        for (int j = 0; j < 4; j++) {
            const float* wr = w_qkv + (size_t)(k0 + j) * 768 + c;
            wq[j] = wr[0]; wk[j] = wr[256]; wv[j] = wr[512];
        }
#pragma unroll
        for (int t = 0; t < 32; t++) {
            float4 x = Xs[t * 64 + (k0 >> 2)];
            aq[t] += x.x * wq[0] + x.y * wq[1] + x.z * wq[2] + x.w * wq[3];
            ak[t] += x.x * wk[0] + x.y * wk[1] + x.z * wk[2] + x.w * wk[3];
            av[t] += x.x * wv[0] + x.y * wv[1] + x.z * wv[2] + x.w * wv[3];
        }
    }

    int hh = c >> 5, dd = c & 31;
    int s = t0 >> 9, n0 = t0 & 511;
#pragma unroll
    for (int t = 0; t < 32; t++) {
        size_t tok = (size_t)(t0 + t);
        Qc[tok * 512 + hh * 64 + dd] = f2bf(clip5(aq[t]));
        Kc[tok * 512 + hh * 64 + dd] = f2bf(clip5(ak[t]));
    }
    // Vt: row (s,h,dh), 32 contiguous tokens
    unsigned short vb[32];
#pragma unroll
    for (int t = 0; t < 32; t++) vb[t] = f2bf(av[t]);
    size_t row = ((size_t)(s * H_ + hh) * DH_ + dd);
    uint4* dst = (uint4*)(Vt + row * N_ + n0);
#pragma unroll
    for (int g = 0; g < 4; g++) {
        uint4 u;
        u.x = (unsigned)vb[8 * g + 0] | ((unsigned)vb[8 * g + 1] << 16);
        u.y = (unsigned)vb[8 * g + 2] | ((unsigned)vb[8 * g + 3] << 16);
        u.z = (unsigned)vb[8 * g + 4] | ((unsigned)vb[8 * g + 5] << 16);
        u.w = (unsigned)vb[8 * g + 6] | ((unsigned)vb[8 * g + 7] << 16);
        dst[g] = u;
    }
}

// ---------------------------------------------------------------------------
// Kernel 2b: metadata -> Qc(qm half), Kc(km half) clipped bf16
// ---------------------------------------------------------------------------
__global__ __launch_bounds__(256) void proj_meta(
    const float* __restrict__ metadata,      // [4096,64]
    const float* __restrict__ w_meta_inner,  // [64,512]
    unsigned short* __restrict__ Qc,
    unsigned short* __restrict__ Kc)
{
    __shared__ float4 Xs[32 * 16];  // 32 tokens x 64 ch
    int t0 = blockIdx.x * 32;
    int tid = threadIdx.x;
    const float4* m4 = (const float4*)(metadata + (size_t)t0 * DM_);
    for (int i = tid; i < 32 * 16; i += 256) Xs[i] = m4[i];
    __syncthreads();

    int c = tid;
    float aq[32], ak[32];
#pragma unroll
    for (int t = 0; t < 32; t++) { aq[t] = 0.f; ak[t] = 0.f; }

    for (int k0 = 0; k0 < DM_; k0 += 4) {
        float wq[4], wk[4];
#pragma unroll
        for (int j = 0; j < 4; j++) {
            const float* wr = w_meta_inner + (size_t)(k0 + j) * 512 + c;
            wq[j] = wr[0]; wk[j] = wr[256];
        }
#pragma unroll
        for (int t = 0; t < 32; t++) {
            float4 x = Xs[t * 16 + (k0 >> 2)];
            aq[t] += x.x * wq[0] + x.y * wq[1] + x.z * wq[2] + x.w * wq[3];
            ak[t] += x.x * wk[0] + x.y * wk[1] + x.z * wk[2] + x.w * wk[3];
        }
    }
    int hh = c >> 5, dd = c & 31;
#pragma unroll
    for (int t = 0; t < 32; t++) {
        size_t tok = (size_t)(t0 + t);
        Qc[tok * 512 + hh * 64 + 32 + dd] = f2bf(clip5(aq[t]));
        Kc[tok * 512 + hh * 64 + 32 + dd] = f2bf(clip5(ak[t]));
    }
}

// ---------------------------------------------------------------------------
// Kernel 3: MFMA flash attention. Block = (s, h, qtile of 64). 4 waves split
// the 1536 keys (each wave 12 chunks of 32 keys). S^T = K·Q^T via
// mfma_f32_16x16x32_bf16 (C-layout: col=lane&15 = q) -> per-lane online
// softmax -> P[q][key] LDS roundtrip (b64 write / b128 read) -> O^T += V^T·P.
// Cross-wave combine at the end.
// ---------------------------------------------------------------------------
__global__ __launch_bounds__(256) void attn_mfma(
    const int* __restrict__ topidx,
    const unsigned short* __restrict__ Qc,   // [4096][8][64] bf16
    const unsigned short* __restrict__ Kc,   // [4096][8][64] bf16
    const unsigned short* __restrict__ Vt,   // [8][8][32][512] bf16
    float* __restrict__ AO)                  // [4096][256] f32
{
    const int s   = blockIdx.x;
    const int h   = blockIdx.y;
    const int qt  = blockIdx.z;
    const int tid = threadIdx.x;
    const int w    = tid >> 6;
    const int lane = tid & 63;
    const int c    = lane & 15;
    const int qd   = lane >> 4;
    const float scale = 0.17677669529663687f;  // 1/sqrt(32)

    __shared__ __align__(16) unsigned short Pq[4][64][40];  // [wave][q][key+pad]
    __shared__ __align__(16) float Of[4][32][66];           // [wave][dh][q+pad]
    __shared__ float Ml[4][2][64];                          // [wave][m/l][q]

    const int src0 = topidx[s * WS_ + 0];
    const int srcs[3] = { topidx[s * WS_ + 0], topidx[s * WS_ + 1], topidx[s * WS_ + 2] };

    // Q B-frags [qg][kc], kept in registers for the whole kernel
    bf16x8 qf[4][2];
    {
        const unsigned short* qbase =
            Qc + (size_t)(src0 * N_ + qt * 64) * 512 + h * 64 + qd * 8;
#pragma unroll
        for (int qg = 0; qg < 4; qg++)
#pragma unroll
            for (int kc = 0; kc < 2; kc++)
                qf[qg][kc] = *reinterpret_cast<const bf16x8*>(
                    qbase + (size_t)(qg * 16 + c) * 512 + kc * 32);
    }

    f32x4 oacc[2][4];  // O^T tiles [dh-group][q-group]
    const f32x4 zero4 = {0.f, 0.f, 0.f, 0.f};
#pragma unroll
    for (int mg = 0; mg < 2; mg++)
#pragma unroll
        for (int qg = 0; qg < 4; qg++) oacc[mg][qg] = zero4;
    float mrun[4], lrun[4];
#pragma unroll
    for (int qg = 0; qg < 4; qg++) { mrun[qg] = -3.0e38f; lrun[qg] = 0.f; }

    for (int step = 0; step < 12; step++) {
        const int chunk = step * 4 + w;        // 0..47
        const int src = srcs[chunk >> 4];      // window
        const int klocal = (chunk & 15) * 32;  // key offset within window

        // K A-frags [mg][kc] straight from global
        bf16x8 kf[2][2];
        const unsigned short* kbase =
            Kc + (size_t)(src * N_ + klocal) * 512 + h * 64 + qd * 8;
#pragma unroll
        for (int mg = 0; mg < 2; mg++)
#pragma unroll
            for (int kc = 0; kc < 2; kc++)
                kf[mg][kc] = *reinterpret_cast<const bf16x8*>(
                    kbase + (size_t)(mg * 16 + c) * 512 + kc * 32);

        // V A-frags [mg] straight from global (Vt rows are key-contiguous)
        bf16x8 vf[2];
        const unsigned short* vbase =
            Vt + (size_t)((src * H_ + h) * DH_) * N_ + klocal + qd * 8;
#pragma unroll
        for (int mg = 0; mg < 2; mg++)
            vf[mg] = *reinterpret_cast<const bf16x8*>(vbase + (size_t)(mg * 16 + c) * N_);

        // S^T = K·Q^T : tiles [mg = 16 keys][qg = 16 q]
        f32x4 sacc[2][4];
#pragma unroll
        for (int mg = 0; mg < 2; mg++)
#pragma unroll
            for (int qg = 0; qg < 4; qg++) sacc[mg][qg] = zero4;
#pragma unroll
        for (int kc = 0; kc < 2; kc++)
#pragma unroll
            for (int mg = 0; mg < 2; mg++)
#pragma unroll
                for (int qg = 0; qg < 4; qg++)
                    sacc[mg][qg] = __builtin_amdgcn_mfma_f32_16x16x32_bf16(
                        kf[mg][kc], qf[qg][kc], sacc[mg][qg], 0, 0, 0);

        // online softmax per q-group (this lane's q = qg*16 + c)
#pragma unroll
        for (int qg = 0; qg < 4; qg++) {
            float mx = sacc[0][qg][0];
#pragma unroll
            for (int r = 1; r < 4; r++) mx = fmaxf(mx, sacc[0][qg][r]);
#pragma unroll
            for (int r = 0; r < 4; r++) mx = fmaxf(mx, sacc[1][qg][r]);
            mx = fmaxf(mx, __shfl_xor(mx, 16));
            mx = fmaxf(mx, __shfl_xor(mx, 32));
            float mnew = fmaxf(mrun[qg], mx);
            float alpha = __expf((mrun[qg] - mnew) * scale);
            float msc = mnew * scale;
            float ps = 0.f;
            unsigned short pb[2][4];
#pragma unroll
            for (int mg = 0; mg < 2; mg++)
#pragma unroll
                for (int r = 0; r < 4; r++) {
                    float p = __expf(__builtin_fmaf(sacc[mg][qg][r], scale, -msc));
                    ps += p;
                    pb[mg][r] = f2bf(p);
                }
            ps += __shfl_xor(ps, 16);
            ps += __shfl_xor(ps, 32);
            lrun[qg] = lrun[qg] * alpha + ps;
            mrun[qg] = mnew;
#pragma unroll
            for (int mg = 0; mg < 2; mg++)
#pragma unroll
                for (int r = 0; r < 4; r++) oacc[mg][qg][r] *= alpha;
            // write P (4 consecutive keys per lane) as one b64
#pragma unroll
            for (int mg = 0; mg < 2; mg++) {
                ushort4 u = make_ushort4(pb[mg][0], pb[mg][1], pb[mg][2], pb[mg][3]);
                *reinterpret_cast<ushort4*>(&Pq[w][qg * 16 + c][mg * 16 + qd * 4]) = u;
            }
        }

        // P B-frags (contiguous b128) and PV MFMAs
        bf16x8 pf[4];
#pragma unroll
        for (int qg = 0; qg < 4; qg++)
            pf[qg] = *reinterpret_cast<const bf16x8*>(&Pq[w][qg * 16 + c][qd * 8]);
#pragma unroll
        for (int mg = 0; mg < 2; mg++)
#pragma unroll
            for (int qg = 0; qg < 4; qg++)
                oacc[mg][qg] = __builtin_amdgcn_mfma_f32_16x16x32_bf16(
                    vf[mg], pf[qg], oacc[mg][qg], 0, 0, 0);
    }

    __syncthreads();
    // dump per-wave partials
#pragma unroll
    for (int qg = 0; qg < 4; qg++) {
        if (qd == 0) {
            Ml[w][0][qg * 16 + c] = mrun[qg];
            Ml[w][1][qg * 16 + c] = lrun[qg];
        }
#pragma unroll
        for (int mg = 0; mg < 2; mg++)
#pragma unroll
            for (int r = 0; r < 4; r++)
                Of[w][mg * 16 + qd * 4 + r][qg * 16 + c] = oacc[mg][qg][r];
    }
    __syncthreads();

    // combine 4 wave partials -> AO
    {
        int q = tid & 63;
        int dh0 = (tid >> 6) * 8;
        float mw[4], cw[4];
#pragma unroll
        for (int v = 0; v < 4; v++) mw[v] = Ml[v][0][q];
        float M = fmaxf(fmaxf(mw[0], mw[1]), fmaxf(mw[2], mw[3]));
        float L = 0.f;
#pragma unroll
        for (int v = 0; v < 4; v++) {
            cw[v] = __expf((mw[v] - M) * scale);
            L += cw[v] * Ml[v][1][q];
        }
        float inv = 1.0f / L;
        float* aorow = AO + (size_t)(s * N_ + qt * 64 + q) * 256 + h * 32;
#pragma unroll
        for (int j = 0; j < 8; j++) {
            int dh = dh0 + j;
            float o = cw[0] * Of[0][dh][q] + cw[1] * Of[1][dh][q]
                    + cw[2] * Of[2][dh][q] + cw[3] * Of[3][dh][q];
            aorow[dh] = o * inv;
        }
    }
}

// ---------------------------------------------------------------------------
// Kernel 4: output projection AO @ w_out + b_out -> out
// ---------------------------------------------------------------------------
__global__ __launch_bounds__(256) void out_proj(
    const float* __restrict__ AO,     // [4096,256]
    const float* __restrict__ w_out,  // [256,256]
    const float* __restrict__ b_out,  // [256]
    float* __restrict__ out)          // [4096,256]
{
    __shared__ float4 Xs[32 * 64];
    int t0 = blockIdx.x * 32;
    int tid = threadIdx.x;
    const float4* a4 = (const float4*)(AO + (size_t)t0 * INNER_);
    for (int i = tid; i < 32 * 64; i += 256) Xs[i] = a4[i];
    __syncthreads();

    int c = tid;
    float acc[32];
#pragma unroll
    for (int t = 0; t < 32; t++) acc[t] = 0.f;

    for (int k0 = 0; k0 < INNER_; k0 += 4) {
        float w0 = w_out[(size_t)(k0 + 0) * 256 + c];
        float w1 = w_out[(size_t)(k0 + 1) * 256 + c];
        float w2 = w_out[(size_t)(k0 + 2) * 256 + c];
        float w3 = w_out[(size_t)(k0 + 3) * 256 + c];
#pragma unroll
        for (int t = 0; t < 32; t++) {
            float4 x = Xs[t * 64 + (k0 >> 2)];
            acc[t] += x.x * w0 + x.y * w1 + x.z * w2 + x.w * w3;
        }
    }
    float b = b_out[c];
#pragma unroll
    for (int t = 0; t < 32; t++) {
        out[(size_t)(t0 + t) * 256 + c] = acc[t] + b;
    }
}

// ---------------------------------------------------------------------------
extern "C" void kernel_launch(void* const* d_in, const int* in_sizes, int n_in,
                              void* d_out, int out_size, void* d_ws, size_t ws_size,
                              hipStream_t stream) {
    const float* values       = (const float*)d_in[0];  // [1,8,512,256]
    const float* metadata     = (const float*)d_in[1];  // [1,8,512,64]
    const float* w_meta_outer = (const float*)d_in[2];  // [64,512]
    const float* w_qkv        = (const float*)d_in[3];  // [256,768]
    const float* w_meta_inner = (const float*)d_in[4];  // [64,512]
    const float* w_out        = (const float*)d_in[5];  // [256,256]
    const float* b_out        = (const float*)d_in[6];  // [256]
    float* out = (float*)d_out;

    int* topidx = (int*)d_ws;
    unsigned short* Qc = (unsigned short*)((char*)d_ws + 256);   // 4096*512 bf16
    unsigned short* Kc = Qc + (size_t)4096 * 512;                // 4096*512 bf16
    unsigned short* Vt = Kc + (size_t)4096 * 512;                // 8*8*32*512 bf16
    float* AO = (float*)(Vt + (size_t)8 * 8 * 32 * 512);         // 4096*256 f32

    outer_topk<<<dim3(1), dim3(256), 0, stream>>>(metadata, w_meta_outer, topidx);
    proj_qkv<<<dim3(128), dim3(256), 0, stream>>>(values, w_qkv, Qc, Kc, Vt);
    proj_meta<<<dim3(128), dim3(256), 0, stream>>>(metadata, w_meta_inner, Qc, Kc);
    attn_mfma<<<dim3(8, 8, 8), dim3(256), 0, stream>>>(topidx, Qc, Kc, Vt, AO);
    out_proj<<<dim3(128), dim3(256), 0, stream>>>(AO, w_out, b_out, out);
}

// Round 3
// 145.108 us; speedup vs baseline: 4.7217x; 2.2831x over previous
//
#include <hip/hip_runtime.h>
#include <hip/hip_bf16.h>

// B=1, S=8, N=512, DV=256, DM=64, INNER=256, H=8, WS=3, DH=32
#define S_ 8
#define N_ 512
#define DV_ 256
#define DM_ 64
#define INNER_ 256
#define H_ 8
#define WS_ 3
#define DH_ 32

typedef __attribute__((ext_vector_type(8))) __bf16 bf16x8;
typedef __attribute__((ext_vector_type(4))) float f32x4;

__device__ __forceinline__ float clip5(float x) {
    return fminf(5.0f, fmaxf(-5.0f, x));
}
__device__ __forceinline__ unsigned short f2bf(float x) {
    __hip_bfloat16 h = __float2bfloat16(x);
    return *reinterpret_cast<unsigned short*>(&h);
}

// ---------------------------------------------------------------------------
// Kernel 0: prep — weight transposes (f32 -> bf16 W^T[n][k]) + meta_mean
// blocks 0..47: w_qkv [256][768] -> WqkvT [768][256]
// blocks 48..55: w_meta_inner [64][512] -> WmetaT [512][64]
// blocks 56..71: w_out [256][256] -> WoutT [256][256]
// blocks 72..79: meta_mean per s -> mm [8][64] f32
// ---------------------------------------------------------------------------
__global__ __launch_bounds__(256) void prep(
    const float* __restrict__ w_qkv, const float* __restrict__ w_meta_inner,
    const float* __restrict__ w_out, const float* __restrict__ metadata,
    unsigned short* __restrict__ WqkvT, unsigned short* __restrict__ WmetaT,
    unsigned short* __restrict__ WoutT, float* __restrict__ mm)
{
    __shared__ float Tf[64][65];
    int b = blockIdx.x, tid = threadIdx.x;
    if (b < 72) {
        const float* src; unsigned short* dst; int Nsrc, Ktot, k0, n0;
        if (b < 48)      { src = w_qkv;        dst = WqkvT; Nsrc = 768; Ktot = 256; k0 = (b & 3) * 64; n0 = (b >> 2) * 64; }
        else if (b < 56) { src = w_meta_inner; dst = WmetaT; Nsrc = 512; Ktot = 64;  k0 = 0;            n0 = (b - 48) * 64; }
        else             { int t = b - 56; src = w_out; dst = WoutT; Nsrc = 256; Ktot = 256; k0 = (t & 3) * 64; n0 = (t >> 2) * 64; }
#pragma unroll
        for (int p = 0; p < 16; p++) {
            int i = p * 256 + tid; int r = i >> 6, cc = i & 63;
            Tf[r][cc] = src[(size_t)(k0 + r) * Nsrc + n0 + cc];
        }
        __syncthreads();
#pragma unroll
        for (int p = 0; p < 16; p++) {
            int i = p * 256 + tid; int r = i >> 6, cc = i & 63;
            dst[(size_t)(n0 + r) * Ktot + k0 + cc] = f2bf(Tf[cc][r]);
        }
    } else {
        int s = b - 72;
        int d = tid & 63, g = tid >> 6;
        const float* base = metadata + ((size_t)(s * N_) + g * 128) * DM_ + d;
        float acc = 0.f;
        for (int i = 0; i < 128; i++) acc += base[(size_t)i * DM_];
        float* red = &Tf[0][0];
        red[tid] = acc;
        __syncthreads();
        if (tid < 64)
            mm[s * 64 + tid] = (red[tid] + red[tid + 64] + red[tid + 128] + red[tid + 192]) * (1.0f / N_);
    }
}

// ---------------------------------------------------------------------------
// Kernel 1: outer metadata attention + top-3 window selection (1 block)
// ---------------------------------------------------------------------------
__global__ __launch_bounds__(256) void outer_topk(
    const float* __restrict__ mm_g,          // [8,64] precomputed mean
    const float* __restrict__ w_meta_outer,  // [64,512]
    int* __restrict__ topidx)                // [8,3]
{
    __shared__ float mm[S_][DM_];
    __shared__ float qmS[S_][INNER_];
    __shared__ float kmS[S_][INNER_];
    __shared__ float dots[S_][S_];
    int tid = threadIdx.x;

    for (int i = tid; i < S_ * DM_; i += 256) ((float*)mm)[i] = mm_g[i];
    __syncthreads();

    for (int i = tid; i < S_ * 2 * INNER_; i += 256) {
        int s = i >> 9, c = i & 511;
        float acc = 0.0f;
        for (int k = 0; k < DM_; k++) acc += mm[s][k] * w_meta_outer[k * 512 + c];
        acc = clip5(acc);
        if (c < INNER_) qmS[s][c] = acc; else kmS[s][c - INNER_] = acc;
    }
    __syncthreads();

    if (tid < 64) {
        int qi = tid >> 3, ki = tid & 7;
        float acc = 0.0f;
        for (int j = 0; j < INNER_; j++) acc += qmS[qi][j] * kmS[ki][j];
        dots[qi][ki] = acc * 0.0625f;  // 1/sqrt(256)
    }
    __syncthreads();

    if (tid < S_) {
        int r = tid;
        float mx = -1e30f;
        for (int k = 0; k < S_; k++) mx = fmaxf(mx, dots[r][k]);
        float e[S_], sum = 0.0f;
        for (int k = 0; k < S_; k++) { e[k] = __expf(dots[r][k] - mx); sum += e[k]; }
        float vals[S_];
        for (int k = 0; k < S_; k++) vals[k] = e[k] / sum + (k == r ? 2.0f : 0.0f);
        bool used[S_];
        for (int k = 0; k < S_; k++) used[k] = false;
        for (int w = 0; w < WS_; w++) {
            float best = -1e30f; int bi = 0;
            for (int k = 0; k < S_; k++) {
                if (!used[k] && vals[k] > best) { best = vals[k]; bi = k; }
            }
            used[bi] = true;
            topidx[r * WS_ + w] = bi;
        }
    }
}

// ---------------------------------------------------------------------------
// Kernel 2: templated MFMA GEMM, 64x64 tile per block (4 waves, 32x32 each).
// ROLE 0: values[4096,256] f32 @ WqkvT -> Qc/Kc (clip, qp|kp halves) + Vt
// ROLE 1: metadata[4096,64] f32 @ WmetaT -> Qc/Kc (clip, qm|km halves)
// ROLE 2: AO[4096,256] bf16 @ WoutT + b_out -> out f32
// A-frag: [m][k] row-major contiguous; B-frag: W^T[n][k] row-major contiguous.
// ---------------------------------------------------------------------------
template<int ROLE>
__global__ __launch_bounds__(256) void gemm_mfma(
    const void* __restrict__ Ag, const unsigned short* __restrict__ Bt,
    unsigned short* __restrict__ Qc, unsigned short* __restrict__ Kc,
    unsigned short* __restrict__ Vt, const float* __restrict__ bias,
    float* __restrict__ outp)
{
    constexpr int K = (ROLE == 1) ? 64 : 256;
    constexpr int KP = K + 8;  // +16B pad: 2-way LDS aliasing only (free)
    __shared__ unsigned short As[64 * KP];
    __shared__ unsigned short Bs[64 * KP];
    const int tid = threadIdx.x;
    const int m0 = blockIdx.x * 64;
    const int n0g = blockIdx.y * 64;

    if (ROLE == 2) {
        const unsigned short* A = (const unsigned short*)Ag;
        for (int i = tid; i < 64 * (K / 8); i += 256) {
            int r = i / (K / 8), g = i % (K / 8);
            *(bf16x8*)&As[r * KP + 8 * g] =
                *(const bf16x8*)(A + (size_t)(m0 + r) * K + 8 * g);
        }
    } else {
        const float* A = (const float*)Ag;
        for (int i = tid; i < 64 * (K / 4); i += 256) {
            int r = i / (K / 4), g = i % (K / 4);
            float4 x = *(const float4*)(A + (size_t)(m0 + r) * K + 4 * g);
            ushort4 u = make_ushort4(f2bf(x.x), f2bf(x.y), f2bf(x.z), f2bf(x.w));
            *(ushort4*)&As[r * KP + 4 * g] = u;
        }
    }
    for (int i = tid; i < 64 * (K / 8); i += 256) {
        int r = i / (K / 8), g = i % (K / 8);
        *(bf16x8*)&Bs[r * KP + 8 * g] =
            *(const bf16x8*)(Bt + (size_t)(n0g + r) * K + 8 * g);
    }
    __syncthreads();

    const int w = tid >> 6, lane = tid & 63, c = lane & 15, qd = lane >> 4;
    const int mb = (w >> 1) * 32, nb = (w & 1) * 32;
    f32x4 acc[2][2];
    const f32x4 z = {0.f, 0.f, 0.f, 0.f};
#pragma unroll
    for (int mt = 0; mt < 2; mt++)
#pragma unroll
        for (int nt = 0; nt < 2; nt++) acc[mt][nt] = z;

#pragma unroll
    for (int kk = 0; kk < K / 32; kk++) {
        bf16x8 a[2], bb[2];
#pragma unroll
        for (int mt = 0; mt < 2; mt++)
            a[mt] = *(const bf16x8*)&As[(mb + mt * 16 + c) * KP + kk * 32 + qd * 8];
#pragma unroll
        for (int nt = 0; nt < 2; nt++)
            bb[nt] = *(const bf16x8*)&Bs[(nb + nt * 16 + c) * KP + kk * 32 + qd * 8];
#pragma unroll
        for (int mt = 0; mt < 2; mt++)
#pragma unroll
            for (int nt = 0; nt < 2; nt++)
                acc[mt][nt] = __builtin_amdgcn_mfma_f32_16x16x32_bf16(
                    a[mt], bb[nt], acc[mt][nt], 0, 0, 0);
    }

#pragma unroll
    for (int mt = 0; mt < 2; mt++)
#pragma unroll
        for (int nt = 0; nt < 2; nt++)
#pragma unroll
            for (int r = 0; r < 4; r++) {
                int tok = m0 + mb + mt * 16 + qd * 4 + r;
                int n = n0g + nb + nt * 16 + c;
                float v = acc[mt][nt][r];
                if (ROLE == 0) {
                    if (n < 512) {
                        unsigned short* dst = (n < 256) ? Qc : Kc;
                        int p = n & 255;
                        dst[(size_t)tok * 512 + (p >> 5) * 64 + (p & 31)] = f2bf(clip5(v));
                    } else {
                        int vc = n - 512, h = vc >> 5, dh = vc & 31;
                        int s = tok >> 9, ntok = tok & 511;
                        Vt[(size_t)((s * 8 + h) * 32 + dh) * 512 + ntok] = f2bf(v);
                    }
                } else if (ROLE == 1) {
                    unsigned short* dst = (n < 256) ? Qc : Kc;
                    int p = n & 255;
                    dst[(size_t)tok * 512 + (p >> 5) * 64 + 32 + (p & 31)] = f2bf(clip5(v));
                } else {
                    outp[(size_t)tok * 256 + n] = v + bias[n];
                }
            }
}

// ---------------------------------------------------------------------------
// Kernel 3: MFMA flash attention (unchanged math from round 2; AO now bf16)
// ---------------------------------------------------------------------------
__global__ __launch_bounds__(256) void attn_mfma(
    const int* __restrict__ topidx,
    const unsigned short* __restrict__ Qc,   // [4096][8][64] bf16
    const unsigned short* __restrict__ Kc,   // [4096][8][64] bf16
    const unsigned short* __restrict__ Vt,   // [8][8][32][512] bf16
    unsigned short* __restrict__ AO)         // [4096][256] bf16
{
    const int s   = blockIdx.x;
    const int h   = blockIdx.y;
    const int qt  = blockIdx.z;
    const int tid = threadIdx.x;
    const int w    = tid >> 6;
    const int lane = tid & 63;
    const int c    = lane & 15;
    const int qd   = lane >> 4;
    const float scale = 0.17677669529663687f;  // 1/sqrt(32)

    __shared__ __align__(16) unsigned short Pq[4][64][40];  // [wave][q][key+pad]
    __shared__ __align__(16) float Of[4][32][66];           // [wave][dh][q+pad]
    __shared__ float Ml[4][2][64];                          // [wave][m/l][q]

    const int src0 = topidx[s * WS_ + 0];
    const int srcs[3] = { topidx[s * WS_ + 0], topidx[s * WS_ + 1], topidx[s * WS_ + 2] };

    bf16x8 qf[4][2];
    {
        const unsigned short* qbase =
            Qc + (size_t)(src0 * N_ + qt * 64) * 512 + h * 64 + qd * 8;
#pragma unroll
        for (int qg = 0; qg < 4; qg++)
#pragma unroll
            for (int kc = 0; kc < 2; kc++)
                qf[qg][kc] = *reinterpret_cast<const bf16x8*>(
                    qbase + (size_t)(qg * 16 + c) * 512 + kc * 32);
    }

    f32x4 oacc[2][4];
    const f32x4 zero4 = {0.f, 0.f, 0.f, 0.f};
#pragma unroll
    for (int mg = 0; mg < 2; mg++)
#pragma unroll
        for (int qg = 0; qg < 4; qg++) oacc[mg][qg] = zero4;
    float mrun[4], lrun[4];
#pragma unroll
    for (int qg = 0; qg < 4; qg++) { mrun[qg] = -3.0e38f; lrun[qg] = 0.f; }

    for (int step = 0; step < 12; step++) {
        const int chunk = step * 4 + w;
        const int src = srcs[chunk >> 4];
        const int klocal = (chunk & 15) * 32;

        bf16x8 kf[2][2];
        const unsigned short* kbase =
            Kc + (size_t)(src * N_ + klocal) * 512 + h * 64 + qd * 8;
#pragma unroll
        for (int mg = 0; mg < 2; mg++)
#pragma unroll
            for (int kc = 0; kc < 2; kc++)
                kf[mg][kc] = *reinterpret_cast<const bf16x8*>(
                    kbase + (size_t)(mg * 16 + c) * 512 + kc * 32);

        bf16x8 vf[2];
        const unsigned short* vbase =
            Vt + (size_t)((src * H_ + h) * DH_) * N_ + klocal + qd * 8;
#pragma unroll
        for (int mg = 0; mg < 2; mg++)
            vf[mg] = *reinterpret_cast<const bf16x8*>(vbase + (size_t)(mg * 16 + c) * N_);

        f32x4 sacc[2][4];
#pragma unroll
        for (int mg = 0; mg < 2; mg++)
#pragma unroll
            for (int qg = 0; qg < 4; qg++) sacc[mg][qg] = zero4;
#pragma unroll
        for (int kc = 0; kc < 2; kc++)
#pragma unroll
            for (int mg = 0; mg < 2; mg++)
#pragma unroll
                for (int qg = 0; qg < 4; qg++)
                    sacc[mg][qg] = __builtin_amdgcn_mfma_f32_16x16x32_bf16(
                        kf[mg][kc], qf[qg][kc], sacc[mg][qg], 0, 0, 0);

#pragma unroll
        for (int qg = 0; qg < 4; qg++) {
            float mx = sacc[0][qg][0];
#pragma unroll
            for (int r = 1; r < 4; r++) mx = fmaxf(mx, sacc[0][qg][r]);
#pragma unroll
            for (int r = 0; r < 4; r++) mx = fmaxf(mx, sacc[1][qg][r]);
            mx = fmaxf(mx, __shfl_xor(mx, 16));
            mx = fmaxf(mx, __shfl_xor(mx, 32));
            float mnew = fmaxf(mrun[qg], mx);
            float alpha = __expf((mrun[qg] - mnew) * scale);
            float msc = mnew * scale;
            float ps = 0.f;
            unsigned short pb[2][4];
#pragma unroll
            for (int mg = 0; mg < 2; mg++)
#pragma unroll
                for (int r = 0; r < 4; r++) {
                    float p = __expf(__builtin_fmaf(sacc[mg][qg][r], scale, -msc));
                    ps += p;
                    pb[mg][r] = f2bf(p);
                }
            ps += __shfl_xor(ps, 16);
            ps += __shfl_xor(ps, 32);
            lrun[qg] = lrun[qg] * alpha + ps;
            mrun[qg] = mnew;
#pragma unroll
            for (int mg = 0; mg < 2; mg++)
#pragma unroll
                for (int r = 0; r < 4; r++) oacc[mg][qg][r] *= alpha;
#pragma unroll
            for (int mg = 0; mg < 2; mg++) {
                ushort4 u = make_ushort4(pb[mg][0], pb[mg][1], pb[mg][2], pb[mg][3]);
                *reinterpret_cast<ushort4*>(&Pq[w][qg * 16 + c][mg * 16 + qd * 4]) = u;
            }
        }

        bf16x8 pf[4];
#pragma unroll
        for (int qg = 0; qg < 4; qg++)
            pf[qg] = *reinterpret_cast<const bf16x8*>(&Pq[w][qg * 16 + c][qd * 8]);
#pragma unroll
        for (int mg = 0; mg < 2; mg++)
#pragma unroll
            for (int qg = 0; qg < 4; qg++)
                oacc[mg][qg] = __builtin_amdgcn_mfma_f32_16x16x32_bf16(
                    vf[mg], pf[qg], oacc[mg][qg], 0, 0, 0);
    }

    __syncthreads();
#pragma unroll
    for (int qg = 0; qg < 4; qg++) {
        if (qd == 0) {
            Ml[w][0][qg * 16 + c] = mrun[qg];
            Ml[w][1][qg * 16 + c] = lrun[qg];
        }
#pragma unroll
        for (int mg = 0; mg < 2; mg++)
#pragma unroll
            for (int r = 0; r < 4; r++)
                Of[w][mg * 16 + qd * 4 + r][qg * 16 + c] = oacc[mg][qg][r];
    }
    __syncthreads();

    {
        int q = tid & 63;
        int dh0 = (tid >> 6) * 8;
        float mw[4], cw[4];
#pragma unroll
        for (int v = 0; v < 4; v++) mw[v] = Ml[v][0][q];
        float M = fmaxf(fmaxf(mw[0], mw[1]), fmaxf(mw[2], mw[3]));
        float L = 0.f;
#pragma unroll
        for (int v = 0; v < 4; v++) {
            cw[v] = __expf((mw[v] - M) * scale);
            L += cw[v] * Ml[v][1][q];
        }
        float inv = 1.0f / L;
        unsigned short* aorow =
            AO + (size_t)(s * N_ + qt * 64 + q) * 256 + h * 32 + dh0;
        unsigned short ub[8];
#pragma unroll
        for (int j = 0; j < 8; j++) {
            int dh = dh0 + j;
            float o = cw[0] * Of[0][dh][q] + cw[1] * Of[1][dh][q]
                    + cw[2] * Of[2][dh][q] + cw[3] * Of[3][dh][q];
            ub[j] = f2bf(o * inv);
        }
        uint4 u;
        u.x = (unsigned)ub[0] | ((unsigned)ub[1] << 16);
        u.y = (unsigned)ub[2] | ((unsigned)ub[3] << 16);
        u.z = (unsigned)ub[4] | ((unsigned)ub[5] << 16);
        u.w = (unsigned)ub[6] | ((unsigned)ub[7] << 16);
        *reinterpret_cast<uint4*>(aorow) = u;
    }
}

// ---------------------------------------------------------------------------
extern "C" void kernel_launch(void* const* d_in, const int* in_sizes, int n_in,
                              void* d_out, int out_size, void* d_ws, size_t ws_size,
                              hipStream_t stream) {
    const float* values       = (const float*)d_in[0];  // [1,8,512,256]
    const float* metadata     = (const float*)d_in[1];  // [1,8,512,64]
    const float* w_meta_outer = (const float*)d_in[2];  // [64,512]
    const float* w_qkv        = (const float*)d_in[3];  // [256,768]
    const float* w_meta_inner = (const float*)d_in[4];  // [64,512]
    const float* w_out        = (const float*)d_in[5];  // [256,256]
    const float* b_out        = (const float*)d_in[6];  // [256]
    float* out = (float*)d_out;

    char* ws = (char*)d_ws;
    int* topidx = (int*)ws;                                    // 128 B
    float* mm = (float*)(ws + 256);                            // 2 KB
    unsigned short* WqkvT  = (unsigned short*)(ws + 4096);     // 768*256 bf16
    unsigned short* WmetaT = WqkvT + (size_t)768 * 256;        // 512*64
    unsigned short* WoutT  = WmetaT + (size_t)512 * 64;        // 256*256
    unsigned short* Qc     = WoutT + (size_t)256 * 256;        // 4096*512
    unsigned short* Kc     = Qc + (size_t)4096 * 512;          // 4096*512
    unsigned short* Vt     = Kc + (size_t)4096 * 512;          // 8*8*32*512
    unsigned short* AO     = Vt + (size_t)8 * 8 * 32 * 512;    // 4096*256

    prep<<<dim3(80), dim3(256), 0, stream>>>(
        w_qkv, w_meta_inner, w_out, metadata, WqkvT, WmetaT, WoutT, mm);
    outer_topk<<<dim3(1), dim3(256), 0, stream>>>(mm, w_meta_outer, topidx);
    gemm_mfma<0><<<dim3(64, 12), dim3(256), 0, stream>>>(
        values, WqkvT, Qc, Kc, Vt, nullptr, nullptr);
    gemm_mfma<1><<<dim3(64, 8), dim3(256), 0, stream>>>(
        metadata, WmetaT, Qc, Kc, Vt, nullptr, nullptr);
    attn_mfma<<<dim3(8, 8, 8), dim3(256), 0, stream>>>(topidx, Qc, Kc, Vt, AO);
    gemm_mfma<2><<<dim3(64, 4), dim3(256), 0, stream>>>(
        AO, WoutT, Qc, Kc, Vt, b_out, out);
}

// Round 4
// 127.548 us; speedup vs baseline: 5.3718x; 1.1377x over previous
//
#include <hip/hip_runtime.h>
#include <hip/hip_bf16.h>

// B=1, S=8, N=512, DV=256, DM=64, INNER=256, H=8, WS=3, DH=32
#define S_ 8
#define N_ 512
#define DV_ 256
#define DM_ 64
#define INNER_ 256
#define H_ 8
#define WS_ 3
#define DH_ 32

typedef __attribute__((ext_vector_type(8))) __bf16 bf16x8;
typedef __attribute__((ext_vector_type(4))) float f32x4;

__device__ __forceinline__ float clip5(float x) {
    return fminf(5.0f, fmaxf(-5.0f, x));
}
__device__ __forceinline__ unsigned short f2bf(float x) {
    __hip_bfloat16 h = __float2bfloat16(x);
    return *reinterpret_cast<unsigned short*>(&h);
}

// ---------------------------------------------------------------------------
// Kernel 0: prep — weight transposes (f32 -> bf16 W^T[n][k]) + meta_mean
// blocks 0..47: w_qkv [256][768] -> WqkvT [768][256]
// blocks 48..55: w_meta_inner [64][512] -> WmetaT [512][64]
// blocks 56..71: w_out [256][256] -> WoutT [256][256]
// blocks 72..79: meta_mean per s -> mm [8][64] f32
// ---------------------------------------------------------------------------
__global__ __launch_bounds__(256) void prep(
    const float* __restrict__ w_qkv, const float* __restrict__ w_meta_inner,
    const float* __restrict__ w_out, const float* __restrict__ metadata,
    unsigned short* __restrict__ WqkvT, unsigned short* __restrict__ WmetaT,
    unsigned short* __restrict__ WoutT, float* __restrict__ mm)
{
    __shared__ float Tf[64][65];
    int b = blockIdx.x, tid = threadIdx.x;
    if (b < 72) {
        const float* src; unsigned short* dst; int Nsrc, Ktot, k0, n0;
        if (b < 48)      { src = w_qkv;        dst = WqkvT; Nsrc = 768; Ktot = 256; k0 = (b & 3) * 64; n0 = (b >> 2) * 64; }
        else if (b < 56) { src = w_meta_inner; dst = WmetaT; Nsrc = 512; Ktot = 64;  k0 = 0;            n0 = (b - 48) * 64; }
        else             { int t = b - 56; src = w_out; dst = WoutT; Nsrc = 256; Ktot = 256; k0 = (t & 3) * 64; n0 = (t >> 2) * 64; }
#pragma unroll
        for (int p = 0; p < 16; p++) {
            int i = p * 256 + tid; int r = i >> 6, cc = i & 63;
            Tf[r][cc] = src[(size_t)(k0 + r) * Nsrc + n0 + cc];
        }
        __syncthreads();
#pragma unroll
        for (int p = 0; p < 16; p++) {
            int i = p * 256 + tid; int r = i >> 6, cc = i & 63;
            dst[(size_t)(n0 + r) * Ktot + k0 + cc] = f2bf(Tf[cc][r]);
        }
    } else {
        int s = b - 72;
        int d = tid & 63, g = tid >> 6;
        const float* base = metadata + ((size_t)(s * N_) + g * 128) * DM_ + d;
        float acc = 0.f;
        for (int i = 0; i < 128; i++) acc += base[(size_t)i * DM_];
        float* red = &Tf[0][0];
        red[tid] = acc;
        __syncthreads();
        if (tid < 64)
            mm[s * 64 + tid] = (red[tid] + red[tid + 64] + red[tid + 128] + red[tid + 192]) * (1.0f / N_);
    }
}

// ---------------------------------------------------------------------------
// Shared GEMM body (64x64 tile, 4 waves of 32x32), A f32 -> bf16 staged.
// ROLE 0: values @ WqkvT -> Qc/Kc (clip, qp|kp halves) + Vt
// ROLE 1: metadata @ WmetaT -> Qc/Kc (clip, qm|km halves)
// ---------------------------------------------------------------------------
template<int ROLE>
__device__ __forceinline__ void gemm_body(
    unsigned short* smem,
    const float* __restrict__ A, const unsigned short* __restrict__ Bt,
    unsigned short* __restrict__ Qc, unsigned short* __restrict__ Kc,
    unsigned short* __restrict__ Vt,
    int m0, int n0g, int tid)
{
    constexpr int K = (ROLE == 1) ? 64 : 256;
    constexpr int KP = K + 8;  // 16B-aligned rows, 2-way LDS aliasing only (free)
    unsigned short* As = smem;
    unsigned short* Bs = smem + 64 * KP;

    for (int i = tid; i < 64 * (K / 4); i += 256) {
        int r = i / (K / 4), g = i % (K / 4);
        float4 x = *(const float4*)(A + (size_t)(m0 + r) * K + 4 * g);
        *(ushort4*)&As[r * KP + 4 * g] =
            make_ushort4(f2bf(x.x), f2bf(x.y), f2bf(x.z), f2bf(x.w));
    }
    for (int i = tid; i < 64 * (K / 8); i += 256) {
        int r = i / (K / 8), g = i % (K / 8);
        *(bf16x8*)&Bs[r * KP + 8 * g] =
            *(const bf16x8*)(Bt + (size_t)(n0g + r) * K + 8 * g);
    }
    __syncthreads();

    const int w = tid >> 6, lane = tid & 63, c = lane & 15, qd = lane >> 4;
    const int mb = (w >> 1) * 32, nb = (w & 1) * 32;
    f32x4 acc[2][2];
    const f32x4 z = {0.f, 0.f, 0.f, 0.f};
#pragma unroll
    for (int mt = 0; mt < 2; mt++)
#pragma unroll
        for (int nt = 0; nt < 2; nt++) acc[mt][nt] = z;

#pragma unroll
    for (int kk = 0; kk < K / 32; kk++) {
        bf16x8 a[2], bb[2];
#pragma unroll
        for (int mt = 0; mt < 2; mt++)
            a[mt] = *(const bf16x8*)&As[(mb + mt * 16 + c) * KP + kk * 32 + qd * 8];
#pragma unroll
        for (int nt = 0; nt < 2; nt++)
            bb[nt] = *(const bf16x8*)&Bs[(nb + nt * 16 + c) * KP + kk * 32 + qd * 8];
#pragma unroll
        for (int mt = 0; mt < 2; mt++)
#pragma unroll
            for (int nt = 0; nt < 2; nt++)
                acc[mt][nt] = __builtin_amdgcn_mfma_f32_16x16x32_bf16(
                    a[mt], bb[nt], acc[mt][nt], 0, 0, 0);
    }

#pragma unroll
    for (int mt = 0; mt < 2; mt++)
#pragma unroll
        for (int nt = 0; nt < 2; nt++)
#pragma unroll
            for (int r = 0; r < 4; r++) {
                int tok = m0 + mb + mt * 16 + qd * 4 + r;
                int n = n0g + nb + nt * 16 + c;
                float v = acc[mt][nt][r];
                if (ROLE == 0) {
                    if (n < 512) {
                        unsigned short* dst = (n < 256) ? Qc : Kc;
                        int p = n & 255;
                        dst[(size_t)tok * 512 + (p >> 5) * 64 + (p & 31)] = f2bf(clip5(v));
                    } else {
                        int vc = n - 512, h = vc >> 5, dh = vc & 31;
                        int s = tok >> 9, ntok = tok & 511;
                        Vt[(size_t)((s * 8 + h) * 32 + dh) * 512 + ntok] = f2bf(v);
                    }
                } else {
                    unsigned short* dst = (n < 256) ? Qc : Kc;
                    int p = n & 255;
                    dst[(size_t)tok * 512 + (p >> 5) * 64 + 32 + (p & 31)] = f2bf(clip5(v));
                }
            }
}

// ---------------------------------------------------------------------------
// Kernel 1: fused — block 0: outer topk; blocks 1..768: values GEMM;
// blocks 769..1280: metadata GEMM. All independent.
// ---------------------------------------------------------------------------
__global__ __launch_bounds__(256) void fused1(
    const float* __restrict__ values, const float* __restrict__ metadata,
    const unsigned short* __restrict__ WqkvT,
    const unsigned short* __restrict__ WmetaT,
    const float* __restrict__ mm_g, const float* __restrict__ w_meta_outer,
    unsigned short* __restrict__ Qc, unsigned short* __restrict__ Kc,
    unsigned short* __restrict__ Vt, int* __restrict__ topidx)
{
    __shared__ __align__(16) unsigned short smem[2 * 64 * 264];  // 66 KB
    const int b = blockIdx.x, tid = threadIdx.x;

    if (b == 0) {
        // ---- outer metadata attention + top-3 ----
        float* mml  = (float*)smem;            // [8][64]
        float* qmS  = mml + 512;               // [8][256]
        float* kmS  = qmS + 2048;              // [8][256]
        float* dots = kmS + 2048;              // [8][8]
        for (int i = tid; i < 512; i += 256) mml[i] = mm_g[i];
        __syncthreads();
        for (int i = tid; i < S_ * 512; i += 256) {
            int s = i >> 9, c = i & 511;
            float acc = 0.0f;
            for (int k = 0; k < DM_; k++) acc += mml[s * 64 + k] * w_meta_outer[k * 512 + c];
            acc = clip5(acc);
            if (c < 256) qmS[s * 256 + c] = acc; else kmS[s * 256 + c - 256] = acc;
        }
        __syncthreads();
        if (tid < 64) {
            int qi = tid >> 3, ki = tid & 7;
            float acc = 0.0f;
            for (int j = 0; j < INNER_; j++) acc += qmS[qi * 256 + j] * kmS[ki * 256 + j];
            dots[qi * 8 + ki] = acc * 0.0625f;  // 1/sqrt(256)
        }
        __syncthreads();
        if (tid < S_) {
            int r = tid;
            float mx = -1e30f;
            for (int k = 0; k < S_; k++) mx = fmaxf(mx, dots[r * 8 + k]);
            float e[S_], sum = 0.0f;
            for (int k = 0; k < S_; k++) { e[k] = __expf(dots[r * 8 + k] - mx); sum += e[k]; }
            float vals[S_];
            for (int k = 0; k < S_; k++) vals[k] = e[k] / sum + (k == r ? 2.0f : 0.0f);
            bool used[S_];
            for (int k = 0; k < S_; k++) used[k] = false;
            for (int w = 0; w < WS_; w++) {
                float best = -1e30f; int bi = 0;
                for (int k = 0; k < S_; k++) {
                    if (!used[k] && vals[k] > best) { best = vals[k]; bi = k; }
                }
                used[bi] = true;
                topidx[r * WS_ + w] = bi;
            }
        }
    } else if (b <= 768) {
        int g = b - 1;
        gemm_body<0>(smem, values, WqkvT, Qc, Kc, Vt, (g & 63) * 64, (g >> 6) * 64, tid);
    } else {
        int g = b - 769;
        gemm_body<1>(smem, metadata, WmetaT, Qc, Kc, Vt, (g & 63) * 64, (g >> 6) * 64, tid);
    }
}

// ---------------------------------------------------------------------------
// Kernel 2: MFMA flash attention (unchanged math; AO bf16)
// ---------------------------------------------------------------------------
__global__ __launch_bounds__(256) void attn_mfma(
    const int* __restrict__ topidx,
    const unsigned short* __restrict__ Qc,   // [4096][8][64] bf16
    const unsigned short* __restrict__ Kc,   // [4096][8][64] bf16
    const unsigned short* __restrict__ Vt,   // [8][8][32][512] bf16
    unsigned short* __restrict__ AO)         // [4096][256] bf16
{
    const int s   = blockIdx.x;
    const int h   = blockIdx.y;
    const int qt  = blockIdx.z;
    const int tid = threadIdx.x;
    const int w    = tid >> 6;
    const int lane = tid & 63;
    const int c    = lane & 15;
    const int qd   = lane >> 4;
    const float scale = 0.17677669529663687f;  // 1/sqrt(32)

    __shared__ __align__(16) unsigned short Pq[4][64][40];  // [wave][q][key+pad]
    __shared__ __align__(16) float Of[4][32][66];           // [wave][dh][q+pad]
    __shared__ float Ml[4][2][64];                          // [wave][m/l][q]

    const int src0 = topidx[s * WS_ + 0];
    const int srcs[3] = { topidx[s * WS_ + 0], topidx[s * WS_ + 1], topidx[s * WS_ + 2] };

    bf16x8 qf[4][2];
    {
        const unsigned short* qbase =
            Qc + (size_t)(src0 * N_ + qt * 64) * 512 + h * 64 + qd * 8;
#pragma unroll
        for (int qg = 0; qg < 4; qg++)
#pragma unroll
            for (int kc = 0; kc < 2; kc++)
                qf[qg][kc] = *reinterpret_cast<const bf16x8*>(
                    qbase + (size_t)(qg * 16 + c) * 512 + kc * 32);
    }

    f32x4 oacc[2][4];
    const f32x4 zero4 = {0.f, 0.f, 0.f, 0.f};
#pragma unroll
    for (int mg = 0; mg < 2; mg++)
#pragma unroll
        for (int qg = 0; qg < 4; qg++) oacc[mg][qg] = zero4;
    float mrun[4], lrun[4];
#pragma unroll
    for (int qg = 0; qg < 4; qg++) { mrun[qg] = -3.0e38f; lrun[qg] = 0.f; }

    for (int step = 0; step < 12; step++) {
        const int chunk = step * 4 + w;
        const int src = srcs[chunk >> 4];
        const int klocal = (chunk & 15) * 32;

        bf16x8 kf[2][2];
        const unsigned short* kbase =
            Kc + (size_t)(src * N_ + klocal) * 512 + h * 64 + qd * 8;
#pragma unroll
        for (int mg = 0; mg < 2; mg++)
#pragma unroll
            for (int kc = 0; kc < 2; kc++)
                kf[mg][kc] = *reinterpret_cast<const bf16x8*>(
                    kbase + (size_t)(mg * 16 + c) * 512 + kc * 32);

        bf16x8 vf[2];
        const unsigned short* vbase =
            Vt + (size_t)((src * H_ + h) * DH_) * N_ + klocal + qd * 8;
#pragma unroll
        for (int mg = 0; mg < 2; mg++)
            vf[mg] = *reinterpret_cast<const bf16x8*>(vbase + (size_t)(mg * 16 + c) * N_);

        f32x4 sacc[2][4];
#pragma unroll
        for (int mg = 0; mg < 2; mg++)
#pragma unroll
            for (int qg = 0; qg < 4; qg++) sacc[mg][qg] = zero4;
#pragma unroll
        for (int kc = 0; kc < 2; kc++)
#pragma unroll
            for (int mg = 0; mg < 2; mg++)
#pragma unroll
                for (int qg = 0; qg < 4; qg++)
                    sacc[mg][qg] = __builtin_amdgcn_mfma_f32_16x16x32_bf16(
                        kf[mg][kc], qf[qg][kc], sacc[mg][qg], 0, 0, 0);

#pragma unroll
        for (int qg = 0; qg < 4; qg++) {
            float mx = sacc[0][qg][0];
#pragma unroll
            for (int r = 1; r < 4; r++) mx = fmaxf(mx, sacc[0][qg][r]);
#pragma unroll
            for (int r = 0; r < 4; r++) mx = fmaxf(mx, sacc[1][qg][r]);
            mx = fmaxf(mx, __shfl_xor(mx, 16));
            mx = fmaxf(mx, __shfl_xor(mx, 32));
            float mnew = fmaxf(mrun[qg], mx);
            float alpha = __expf((mrun[qg] - mnew) * scale);
            float msc = mnew * scale;
            float ps = 0.f;
            unsigned short pb[2][4];
#pragma unroll
            for (int mg = 0; mg < 2; mg++)
#pragma unroll
                for (int r = 0; r < 4; r++) {
                    float p = __expf(__builtin_fmaf(sacc[mg][qg][r], scale, -msc));
                    ps += p;
                    pb[mg][r] = f2bf(p);
                }
            ps += __shfl_xor(ps, 16);
            ps += __shfl_xor(ps, 32);
            lrun[qg] = lrun[qg] * alpha + ps;
            mrun[qg] = mnew;
#pragma unroll
            for (int mg = 0; mg < 2; mg++)
#pragma unroll
                for (int r = 0; r < 4; r++) oacc[mg][qg][r] *= alpha;
#pragma unroll
            for (int mg = 0; mg < 2; mg++) {
                ushort4 u = make_ushort4(pb[mg][0], pb[mg][1], pb[mg][2], pb[mg][3]);
                *reinterpret_cast<ushort4*>(&Pq[w][qg * 16 + c][mg * 16 + qd * 4]) = u;
            }
        }

        bf16x8 pf[4];
#pragma unroll
        for (int qg = 0; qg < 4; qg++)
            pf[qg] = *reinterpret_cast<const bf16x8*>(&Pq[w][qg * 16 + c][qd * 8]);
#pragma unroll
        for (int mg = 0; mg < 2; mg++)
#pragma unroll
            for (int qg = 0; qg < 4; qg++)
                oacc[mg][qg] = __builtin_amdgcn_mfma_f32_16x16x32_bf16(
                    vf[mg], pf[qg], oacc[mg][qg], 0, 0, 0);
    }

    __syncthreads();
#pragma unroll
    for (int qg = 0; qg < 4; qg++) {
        if (qd == 0) {
            Ml[w][0][qg * 16 + c] = mrun[qg];
            Ml[w][1][qg * 16 + c] = lrun[qg];
        }
#pragma unroll
        for (int mg = 0; mg < 2; mg++)
#pragma unroll
            for (int r = 0; r < 4; r++)
                Of[w][mg * 16 + qd * 4 + r][qg * 16 + c] = oacc[mg][qg][r];
    }
    __syncthreads();

    {
        int q = tid & 63;
        int dh0 = (tid >> 6) * 8;
        float mw[4], cw[4];
#pragma unroll
        for (int v = 0; v < 4; v++) mw[v] = Ml[v][0][q];
        float M = fmaxf(fmaxf(mw[0], mw[1]), fmaxf(mw[2], mw[3]));
        float L = 0.f;
#pragma unroll
        for (int v = 0; v < 4; v++) {
            cw[v] = __expf((mw[v] - M) * scale);
            L += cw[v] * Ml[v][1][q];
        }
        float inv = 1.0f / L;
        unsigned short* aorow =
            AO + (size_t)(s * N_ + qt * 64 + q) * 256 + h * 32 + dh0;
        unsigned short ub[8];
#pragma unroll
        for (int j = 0; j < 8; j++) {
            int dh = dh0 + j;
            float o = cw[0] * Of[0][dh][q] + cw[1] * Of[1][dh][q]
                    + cw[2] * Of[2][dh][q] + cw[3] * Of[3][dh][q];
            ub[j] = f2bf(o * inv);
        }
        uint4 u;
        u.x = (unsigned)ub[0] | ((unsigned)ub[1] << 16);
        u.y = (unsigned)ub[2] | ((unsigned)ub[3] << 16);
        u.z = (unsigned)ub[4] | ((unsigned)ub[5] << 16);
        u.w = (unsigned)ub[6] | ((unsigned)ub[7] << 16);
        *reinterpret_cast<uint4*>(aorow) = u;
    }
}

// ---------------------------------------------------------------------------
// Kernel 3: output projection AO(bf16) @ WoutT + b_out -> out f32
// ---------------------------------------------------------------------------
__global__ __launch_bounds__(256) void gemm_out(
    const unsigned short* __restrict__ AO, const unsigned short* __restrict__ Bt,
    const float* __restrict__ bias, float* __restrict__ outp)
{
    constexpr int K = 256;
    constexpr int KP = K + 8;
    __shared__ __align__(16) unsigned short As[64 * KP];
    __shared__ __align__(16) unsigned short Bs[64 * KP];
    const int tid = threadIdx.x;
    const int m0 = blockIdx.x * 64;
    const int n0g = blockIdx.y * 64;

    for (int i = tid; i < 64 * (K / 8); i += 256) {
        int r = i / (K / 8), g = i % (K / 8);
        *(bf16x8*)&As[r * KP + 8 * g] =
            *(const bf16x8*)(AO + (size_t)(m0 + r) * K + 8 * g);
    }
    for (int i = tid; i < 64 * (K / 8); i += 256) {
        int r = i / (K / 8), g = i % (K / 8);
        *(bf16x8*)&Bs[r * KP + 8 * g] =
            *(const bf16x8*)(Bt + (size_t)(n0g + r) * K + 8 * g);
    }
    __syncthreads();

    const int w = tid >> 6, lane = tid & 63, c = lane & 15, qd = lane >> 4;
    const int mb = (w >> 1) * 32, nb = (w & 1) * 32;
    f32x4 acc[2][2];
    const f32x4 z = {0.f, 0.f, 0.f, 0.f};
#pragma unroll
    for (int mt = 0; mt < 2; mt++)
#pragma unroll
        for (int nt = 0; nt < 2; nt++) acc[mt][nt] = z;

#pragma unroll
    for (int kk = 0; kk < K / 32; kk++) {
        bf16x8 a[2], bb[2];
#pragma unroll
        for (int mt = 0; mt < 2; mt++)
            a[mt] = *(const bf16x8*)&As[(mb + mt * 16 + c) * KP + kk * 32 + qd * 8];
#pragma unroll
        for (int nt = 0; nt < 2; nt++)
            bb[nt] = *(const bf16x8*)&Bs[(nb + nt * 16 + c) * KP + kk * 32 + qd * 8];
#pragma unroll
        for (int mt = 0; mt < 2; mt++)
#pragma unroll
            for (int nt = 0; nt < 2; nt++)
                acc[mt][nt] = __builtin_amdgcn_mfma_f32_16x16x32_bf16(
                    a[mt], bb[nt], acc[mt][nt], 0, 0, 0);
    }

#pragma unroll
    for (int mt = 0; mt < 2; mt++)
#pragma unroll
        for (int nt = 0; nt < 2; nt++)
#pragma unroll
            for (int r = 0; r < 4; r++) {
                int tok = m0 + mb + mt * 16 + qd * 4 + r;
                int n = n0g + nb + nt * 16 + c;
                outp[(size_t)tok * 256 + n] = acc[mt][nt][r] + bias[n];
            }
}

// ---------------------------------------------------------------------------
extern "C" void kernel_launch(void* const* d_in, const int* in_sizes, int n_in,
                              void* d_out, int out_size, void* d_ws, size_t ws_size,
                              hipStream_t stream) {
    const float* values       = (const float*)d_in[0];  // [1,8,512,256]
    const float* metadata     = (const float*)d_in[1];  // [1,8,512,64]
    const float* w_meta_outer = (const float*)d_in[2];  // [64,512]
    const float* w_qkv        = (const float*)d_in[3];  // [256,768]
    const float* w_meta_inner = (const float*)d_in[4];  // [64,512]
    const float* w_out        = (const float*)d_in[5];  // [256,256]
    const float* b_out        = (const float*)d_in[6];  // [256]
    float* out = (float*)d_out;

    char* ws = (char*)d_ws;
    int* topidx = (int*)ws;                                    // 128 B
    float* mm = (float*)(ws + 256);                            // 2 KB
    unsigned short* WqkvT  = (unsigned short*)(ws + 4096);     // 768*256 bf16
    unsigned short* WmetaT = WqkvT + (size_t)768 * 256;        // 512*64
    unsigned short* WoutT  = WmetaT + (size_t)512 * 64;        // 256*256
    unsigned short* Qc     = WoutT + (size_t)256 * 256;        // 4096*512
    unsigned short* Kc     = Qc + (size_t)4096 * 512;          // 4096*512
    unsigned short* Vt     = Kc + (size_t)4096 * 512;          // 8*8*32*512
    unsigned short* AO     = Vt + (size_t)8 * 8 * 32 * 512;    // 4096*256

    prep<<<dim3(80), dim3(256), 0, stream>>>(
        w_qkv, w_meta_inner, w_out, metadata, WqkvT, WmetaT, WoutT, mm);
    fused1<<<dim3(1281), dim3(256), 0, stream>>>(
        values, metadata, WqkvT, WmetaT, mm, w_meta_outer, Qc, Kc, Vt, topidx);
    attn_mfma<<<dim3(8, 8, 8), dim3(256), 0, stream>>>(topidx, Qc, Kc, Vt, AO);
    gemm_out<<<dim3(64, 4), dim3(256), 0, stream>>>(AO, WoutT, b_out, out);
}

// Round 5
// 124.687 us; speedup vs baseline: 5.4951x; 1.0229x over previous
//
#include <hip/hip_runtime.h>
#include <hip/hip_bf16.h>

// B=1, S=8, N=512, DV=256, DM=64, INNER=256, H=8, WS=3, DH=32
#define S_ 8
#define N_ 512
#define DV_ 256
#define DM_ 64
#define INNER_ 256
#define H_ 8
#define WS_ 3
#define DH_ 32

typedef __attribute__((ext_vector_type(8))) __bf16 bf16x8;
typedef __attribute__((ext_vector_type(4))) float f32x4;

__device__ __forceinline__ float clip5(float x) {
    return fminf(5.0f, fmaxf(-5.0f, x));
}
__device__ __forceinline__ unsigned short f2bf(float x) {
    __hip_bfloat16 h = __float2bfloat16(x);
    return *reinterpret_cast<unsigned short*>(&h);
}

// ---------------------------------------------------------------------------
// Kernel 0: prep — weight transposes (f32 -> bf16 W^T[n][k]) + meta_mean parts
// blocks 0..47:  w_qkv [256][768] -> WqkvT [768][256]
// blocks 48..55: w_meta_inner [64][512] -> WmetaT [512][64]
// blocks 56..71: w_out [256][256] -> WoutT [256][256]
// blocks 72..135: meta partial sums: block 72+s*8+g sums tokens [g*64,(g+1)*64)
//                 of source s -> mm_part[s][g][64]
// ---------------------------------------------------------------------------
__global__ __launch_bounds__(256) void prep(
    const float* __restrict__ w_qkv, const float* __restrict__ w_meta_inner,
    const float* __restrict__ w_out, const float* __restrict__ metadata,
    unsigned short* __restrict__ WqkvT, unsigned short* __restrict__ WmetaT,
    unsigned short* __restrict__ WoutT, float* __restrict__ mm_part)
{
    __shared__ float Tf[64][65];
    int b = blockIdx.x, tid = threadIdx.x;
    if (b < 72) {
        const float* src; unsigned short* dst; int Nsrc, Ktot, k0, n0;
        if (b < 48)      { src = w_qkv;        dst = WqkvT; Nsrc = 768; Ktot = 256; k0 = (b & 3) * 64; n0 = (b >> 2) * 64; }
        else if (b < 56) { src = w_meta_inner; dst = WmetaT; Nsrc = 512; Ktot = 64;  k0 = 0;            n0 = (b - 48) * 64; }
        else             { int t = b - 56; src = w_out; dst = WoutT; Nsrc = 256; Ktot = 256; k0 = (t & 3) * 64; n0 = (t >> 2) * 64; }
#pragma unroll
        for (int p = 0; p < 16; p++) {
            int i = p * 256 + tid; int r = i >> 6, cc = i & 63;
            Tf[r][cc] = src[(size_t)(k0 + r) * Nsrc + n0 + cc];
        }
        __syncthreads();
#pragma unroll
        for (int p = 0; p < 16; p++) {
            int i = p * 256 + tid; int r = i >> 6, cc = i & 63;
            dst[(size_t)(n0 + r) * Ktot + k0 + cc] = f2bf(Tf[cc][r]);
        }
    } else {
        int bb = b - 72;          // 0..63
        int s = bb >> 3, g = bb & 7;
        int d = tid & 63, t4 = tid >> 6;
        const float* base = metadata + ((size_t)(s * N_) + g * 64 + t4 * 16) * DM_ + d;
        float acc = 0.f;
#pragma unroll
        for (int i = 0; i < 16; i++) acc += base[(size_t)i * DM_];
        float* red = &Tf[0][0];
        red[tid] = acc;
        __syncthreads();
        if (tid < 64)
            mm_part[(size_t)bb * 64 + tid] =
                red[tid] + red[tid + 64] + red[tid + 128] + red[tid + 192];
    }
}

// ---------------------------------------------------------------------------
// Shared GEMM body (64x64 tile, 4 waves of 32x32), A f32 -> bf16 staged.
// ROLE 0: values @ WqkvT -> Qc/Kc (clip, qp|kp halves) + Vt
// ROLE 1: metadata @ WmetaT -> Qc/Kc (clip, qm|km halves)
// ---------------------------------------------------------------------------
template<int ROLE>
__device__ __forceinline__ void gemm_body(
    unsigned short* smem,
    const float* __restrict__ A, const unsigned short* __restrict__ Bt,
    unsigned short* __restrict__ Qc, unsigned short* __restrict__ Kc,
    unsigned short* __restrict__ Vt,
    int m0, int n0g, int tid)
{
    constexpr int K = (ROLE == 1) ? 64 : 256;
    constexpr int KP = K + 8;  // 16B-aligned rows, 2-way LDS aliasing only (free)
    unsigned short* As = smem;
    unsigned short* Bs = smem + 64 * KP;

    for (int i = tid; i < 64 * (K / 4); i += 256) {
        int r = i / (K / 4), g = i % (K / 4);
        float4 x = *(const float4*)(A + (size_t)(m0 + r) * K + 4 * g);
        *(ushort4*)&As[r * KP + 4 * g] =
            make_ushort4(f2bf(x.x), f2bf(x.y), f2bf(x.z), f2bf(x.w));
    }
    for (int i = tid; i < 64 * (K / 8); i += 256) {
        int r = i / (K / 8), g = i % (K / 8);
        *(bf16x8*)&Bs[r * KP + 8 * g] =
            *(const bf16x8*)(Bt + (size_t)(n0g + r) * K + 8 * g);
    }
    __syncthreads();

    const int w = tid >> 6, lane = tid & 63, c = lane & 15, qd = lane >> 4;
    const int mb = (w >> 1) * 32, nb = (w & 1) * 32;
    f32x4 acc[2][2];
    const f32x4 z = {0.f, 0.f, 0.f, 0.f};
#pragma unroll
    for (int mt = 0; mt < 2; mt++)
#pragma unroll
        for (int nt = 0; nt < 2; nt++) acc[mt][nt] = z;

#pragma unroll
    for (int kk = 0; kk < K / 32; kk++) {
        bf16x8 a[2], bb[2];
#pragma unroll
        for (int mt = 0; mt < 2; mt++)
            a[mt] = *(const bf16x8*)&As[(mb + mt * 16 + c) * KP + kk * 32 + qd * 8];
#pragma unroll
        for (int nt = 0; nt < 2; nt++)
            bb[nt] = *(const bf16x8*)&Bs[(nb + nt * 16 + c) * KP + kk * 32 + qd * 8];
#pragma unroll
        for (int mt = 0; mt < 2; mt++)
#pragma unroll
            for (int nt = 0; nt < 2; nt++)
                acc[mt][nt] = __builtin_amdgcn_mfma_f32_16x16x32_bf16(
                    a[mt], bb[nt], acc[mt][nt], 0, 0, 0);
    }

#pragma unroll
    for (int mt = 0; mt < 2; mt++)
#pragma unroll
        for (int nt = 0; nt < 2; nt++)
#pragma unroll
            for (int r = 0; r < 4; r++) {
                int tok = m0 + mb + mt * 16 + qd * 4 + r;
                int n = n0g + nb + nt * 16 + c;
                float v = acc[mt][nt][r];
                if (ROLE == 0) {
                    if (n < 512) {
                        unsigned short* dst = (n < 256) ? Qc : Kc;
                        int p = n & 255;
                        dst[(size_t)tok * 512 + (p >> 5) * 64 + (p & 31)] = f2bf(clip5(v));
                    } else {
                        int vc = n - 512, h = vc >> 5, dh = vc & 31;
                        int s = tok >> 9, ntok = tok & 511;
                        Vt[(size_t)((s * 8 + h) * 32 + dh) * 512 + ntok] = f2bf(v);
                    }
                } else {
                    unsigned short* dst = (n < 256) ? Qc : Kc;
                    int p = n & 255;
                    dst[(size_t)tok * 512 + (p >> 5) * 64 + 32 + (p & 31)] = f2bf(clip5(v));
                }
            }
}

// ---------------------------------------------------------------------------
// Kernel 1: fused — block 0: mm reduce + outer topk; blocks 1..768: values
// GEMM; blocks 769..1280: metadata GEMM. All independent.
// ---------------------------------------------------------------------------
__global__ __launch_bounds__(256) void fused1(
    const float* __restrict__ values, const float* __restrict__ metadata,
    const unsigned short* __restrict__ WqkvT,
    const unsigned short* __restrict__ WmetaT,
    const float* __restrict__ mm_part, const float* __restrict__ w_meta_outer,
    unsigned short* __restrict__ Qc, unsigned short* __restrict__ Kc,
    unsigned short* __restrict__ Vt, int* __restrict__ topidx)
{
    __shared__ __align__(16) unsigned short smem[2 * 64 * 264];  // 66 KB
    const int b = blockIdx.x, tid = threadIdx.x;

    if (b == 0) {
        // ---- reduce meta_mean partials, then outer attention + top-3 ----
        float* mml  = (float*)smem;            // [8][64]
        float* qmS  = mml + 512;               // [8][256]
        float* kmS  = qmS + 2048;              // [8][256]
        float* dots = kmS + 2048;              // [8][8]
        for (int i = tid; i < 512; i += 256) {
            int s = i >> 6, d = i & 63;
            float acc = 0.f;
#pragma unroll
            for (int g = 0; g < 8; g++) acc += mm_part[(size_t)(s * 8 + g) * 64 + d];
            mml[i] = acc * (1.0f / (float)N_);
        }
        __syncthreads();
        for (int i = tid; i < S_ * 512; i += 256) {
            int s = i >> 9, c = i & 511;
            float acc = 0.0f;
            for (int k = 0; k < DM_; k++) acc += mml[s * 64 + k] * w_meta_outer[k * 512 + c];
            acc = clip5(acc);
            if (c < 256) qmS[s * 256 + c] = acc; else kmS[s * 256 + c - 256] = acc;
        }
        __syncthreads();
        if (tid < 64) {
            int qi = tid >> 3, ki = tid & 7;
            float acc = 0.0f;
            for (int j = 0; j < INNER_; j++) acc += qmS[qi * 256 + j] * kmS[ki * 256 + j];
            dots[qi * 8 + ki] = acc * 0.0625f;  // 1/sqrt(256)
        }
        __syncthreads();
        if (tid < S_) {
            int r = tid;
            float mx = -1e30f;
            for (int k = 0; k < S_; k++) mx = fmaxf(mx, dots[r * 8 + k]);
            float e[S_], sum = 0.0f;
            for (int k = 0; k < S_; k++) { e[k] = __expf(dots[r * 8 + k] - mx); sum += e[k]; }
            float vals[S_];
            for (int k = 0; k < S_; k++) vals[k] = e[k] / sum + (k == r ? 2.0f : 0.0f);
            bool used[S_];
            for (int k = 0; k < S_; k++) used[k] = false;
            for (int w = 0; w < WS_; w++) {
                float best = -1e30f; int bi = 0;
                for (int k = 0; k < S_; k++) {
                    if (!used[k] && vals[k] > best) { best = vals[k]; bi = k; }
                }
                used[bi] = true;
                topidx[r * WS_ + w] = bi;
            }
        }
    } else if (b <= 768) {
        int g = b - 1;
        gemm_body<0>(smem, values, WqkvT, Qc, Kc, Vt, (g & 63) * 64, (g >> 6) * 64, tid);
    } else {
        int g = b - 769;
        gemm_body<1>(smem, metadata, WmetaT, Qc, Kc, Vt, (g & 63) * 64, (g >> 6) * 64, tid);
    }
}

// ---------------------------------------------------------------------------
// Kernel 2: MFMA flash attention (unchanged math; AO bf16)
// ---------------------------------------------------------------------------
__global__ __launch_bounds__(256) void attn_mfma(
    const int* __restrict__ topidx,
    const unsigned short* __restrict__ Qc,   // [4096][8][64] bf16
    const unsigned short* __restrict__ Kc,   // [4096][8][64] bf16
    const unsigned short* __restrict__ Vt,   // [8][8][32][512] bf16
    unsigned short* __restrict__ AO)         // [4096][256] bf16
{
    const int s   = blockIdx.x;
    const int h   = blockIdx.y;
    const int qt  = blockIdx.z;
    const int tid = threadIdx.x;
    const int w    = tid >> 6;
    const int lane = tid & 63;
    const int c    = lane & 15;
    const int qd   = lane >> 4;
    const float scale = 0.17677669529663687f;  // 1/sqrt(32)

    __shared__ __align__(16) unsigned short Pq[4][64][40];  // [wave][q][key+pad]
    __shared__ __align__(16) float Of[4][32][66];           // [wave][dh][q+pad]
    __shared__ float Ml[4][2][64];                          // [wave][m/l][q]

    const int src0 = topidx[s * WS_ + 0];
    const int srcs[3] = { topidx[s * WS_ + 0], topidx[s * WS_ + 1], topidx[s * WS_ + 2] };

    bf16x8 qf[4][2];
    {
        const unsigned short* qbase =
            Qc + (size_t)(src0 * N_ + qt * 64) * 512 + h * 64 + qd * 8;
#pragma unroll
        for (int qg = 0; qg < 4; qg++)
#pragma unroll
            for (int kc = 0; kc < 2; kc++)
                qf[qg][kc] = *reinterpret_cast<const bf16x8*>(
                    qbase + (size_t)(qg * 16 + c) * 512 + kc * 32);
    }

    f32x4 oacc[2][4];
    const f32x4 zero4 = {0.f, 0.f, 0.f, 0.f};
#pragma unroll
    for (int mg = 0; mg < 2; mg++)
#pragma unroll
        for (int qg = 0; qg < 4; qg++) oacc[mg][qg] = zero4;
    float mrun[4], lrun[4];
#pragma unroll
    for (int qg = 0; qg < 4; qg++) { mrun[qg] = -3.0e38f; lrun[qg] = 0.f; }

    for (int step = 0; step < 12; step++) {
        const int chunk = step * 4 + w;
        const int src = srcs[chunk >> 4];
        const int klocal = (chunk & 15) * 32;

        bf16x8 kf[2][2];
        const unsigned short* kbase =
            Kc + (size_t)(src * N_ + klocal) * 512 + h * 64 + qd * 8;
#pragma unroll
        for (int mg = 0; mg < 2; mg++)
#pragma unroll
            for (int kc = 0; kc < 2; kc++)
                kf[mg][kc] = *reinterpret_cast<const bf16x8*>(
                    kbase + (size_t)(mg * 16 + c) * 512 + kc * 32);

        bf16x8 vf[2];
        const unsigned short* vbase =
            Vt + (size_t)((src * H_ + h) * DH_) * N_ + klocal + qd * 8;
#pragma unroll
        for (int mg = 0; mg < 2; mg++)
            vf[mg] = *reinterpret_cast<const bf16x8*>(vbase + (size_t)(mg * 16 + c) * N_);

        f32x4 sacc[2][4];
#pragma unroll
        for (int mg = 0; mg < 2; mg++)
#pragma unroll
            for (int qg = 0; qg < 4; qg++) sacc[mg][qg] = zero4;
#pragma unroll
        for (int kc = 0; kc < 2; kc++)
#pragma unroll
            for (int mg = 0; mg < 2; mg++)
#pragma unroll
                for (int qg = 0; qg < 4; qg++)
                    sacc[mg][qg] = __builtin_amdgcn_mfma_f32_16x16x32_bf16(
                        kf[mg][kc], qf[qg][kc], sacc[mg][qg], 0, 0, 0);

#pragma unroll
        for (int qg = 0; qg < 4; qg++) {
            float mx = sacc[0][qg][0];
#pragma unroll
            for (int r = 1; r < 4; r++) mx = fmaxf(mx, sacc[0][qg][r]);
#pragma unroll
            for (int r = 0; r < 4; r++) mx = fmaxf(mx, sacc[1][qg][r]);
            mx = fmaxf(mx, __shfl_xor(mx, 16));
            mx = fmaxf(mx, __shfl_xor(mx, 32));
            float mnew = fmaxf(mrun[qg], mx);
            float alpha = __expf((mrun[qg] - mnew) * scale);
            float msc = mnew * scale;
            float ps = 0.f;
            unsigned short pb[2][4];
#pragma unroll
            for (int mg = 0; mg < 2; mg++)
#pragma unroll
                for (int r = 0; r < 4; r++) {
                    float p = __expf(__builtin_fmaf(sacc[mg][qg][r], scale, -msc));
                    ps += p;
                    pb[mg][r] = f2bf(p);
                }
            ps += __shfl_xor(ps, 16);
            ps += __shfl_xor(ps, 32);
            lrun[qg] = lrun[qg] * alpha + ps;
            mrun[qg] = mnew;
#pragma unroll
            for (int mg = 0; mg < 2; mg++)
#pragma unroll
                for (int r = 0; r < 4; r++) oacc[mg][qg][r] *= alpha;
#pragma unroll
            for (int mg = 0; mg < 2; mg++) {
                ushort4 u = make_ushort4(pb[mg][0], pb[mg][1], pb[mg][2], pb[mg][3]);
                *reinterpret_cast<ushort4*>(&Pq[w][qg * 16 + c][mg * 16 + qd * 4]) = u;
            }
        }

        bf16x8 pf[4];
#pragma unroll
        for (int qg = 0; qg < 4; qg++)
            pf[qg] = *reinterpret_cast<const bf16x8*>(&Pq[w][qg * 16 + c][qd * 8]);
#pragma unroll
        for (int mg = 0; mg < 2; mg++)
#pragma unroll
            for (int qg = 0; qg < 4; qg++)
                oacc[mg][qg] = __builtin_amdgcn_mfma_f32_16x16x32_bf16(
                    vf[mg], pf[qg], oacc[mg][qg], 0, 0, 0);
    }

    __syncthreads();
#pragma unroll
    for (int qg = 0; qg < 4; qg++) {
        if (qd == 0) {
            Ml[w][0][qg * 16 + c] = mrun[qg];
            Ml[w][1][qg * 16 + c] = lrun[qg];
        }
#pragma unroll
        for (int mg = 0; mg < 2; mg++)
#pragma unroll
            for (int r = 0; r < 4; r++)
                Of[w][mg * 16 + qd * 4 + r][qg * 16 + c] = oacc[mg][qg][r];
    }
    __syncthreads();

    {
        int q = tid & 63;
        int dh0 = (tid >> 6) * 8;
        float mw[4], cw[4];
#pragma unroll
        for (int v = 0; v < 4; v++) mw[v] = Ml[v][0][q];
        float M = fmaxf(fmaxf(mw[0], mw[1]), fmaxf(mw[2], mw[3]));
        float L = 0.f;
#pragma unroll
        for (int v = 0; v < 4; v++) {
            cw[v] = __expf((mw[v] - M) * scale);
            L += cw[v] * Ml[v][1][q];
        }
        float inv = 1.0f / L;
        unsigned short* aorow =
            AO + (size_t)(s * N_ + qt * 64 + q) * 256 + h * 32 + dh0;
        unsigned short ub[8];
#pragma unroll
        for (int j = 0; j < 8; j++) {
            int dh = dh0 + j;
            float o = cw[0] * Of[0][dh][q] + cw[1] * Of[1][dh][q]
                    + cw[2] * Of[2][dh][q] + cw[3] * Of[3][dh][q];
            ub[j] = f2bf(o * inv);
        }
        uint4 u;
        u.x = (unsigned)ub[0] | ((unsigned)ub[1] << 16);
        u.y = (unsigned)ub[2] | ((unsigned)ub[3] << 16);
        u.z = (unsigned)ub[4] | ((unsigned)ub[5] << 16);
        u.w = (unsigned)ub[6] | ((unsigned)ub[7] << 16);
        *reinterpret_cast<uint4*>(aorow) = u;
    }
}

// ---------------------------------------------------------------------------
// Kernel 3: output projection AO(bf16) @ WoutT + b_out -> out f32
// ---------------------------------------------------------------------------
__global__ __launch_bounds__(256) void gemm_out(
    const unsigned short* __restrict__ AO, const unsigned short* __restrict__ Bt,
    const float* __restrict__ bias, float* __restrict__ outp)
{
    constexpr int K = 256;
    constexpr int KP = K + 8;
    __shared__ __align__(16) unsigned short As[64 * KP];
    __shared__ __align__(16) unsigned short Bs[64 * KP];
    const int tid = threadIdx.x;
    const int m0 = blockIdx.x * 64;
    const int n0g = blockIdx.y * 64;

    for (int i = tid; i < 64 * (K / 8); i += 256) {
        int r = i / (K / 8), g = i % (K / 8);
        *(bf16x8*)&As[r * KP + 8 * g] =
            *(const bf16x8*)(AO + (size_t)(m0 + r) * K + 8 * g);
    }
    for (int i = tid; i < 64 * (K / 8); i += 256) {
        int r = i / (K / 8), g = i % (K / 8);
        *(bf16x8*)&Bs[r * KP + 8 * g] =
            *(const bf16x8*)(Bt + (size_t)(n0g + r) * K + 8 * g);
    }
    __syncthreads();

    const int w = tid >> 6, lane = tid & 63, c = lane & 15, qd = lane >> 4;
    const int mb = (w >> 1) * 32, nb = (w & 1) * 32;
    f32x4 acc[2][2];
    const f32x4 z = {0.f, 0.f, 0.f, 0.f};
#pragma unroll
    for (int mt = 0; mt < 2; mt++)
#pragma unroll
        for (int nt = 0; nt < 2; nt++) acc[mt][nt] = z;

#pragma unroll
    for (int kk = 0; kk < K / 32; kk++) {
        bf16x8 a[2], bb[2];
#pragma unroll
        for (int mt = 0; mt < 2; mt++)
            a[mt] = *(const bf16x8*)&As[(mb + mt * 16 + c) * KP + kk * 32 + qd * 8];
#pragma unroll
        for (int nt = 0; nt < 2; nt++)
            bb[nt] = *(const bf16x8*)&Bs[(nb + nt * 16 + c) * KP + kk * 32 + qd * 8];
#pragma unroll
        for (int mt = 0; mt < 2; mt++)
#pragma unroll
            for (int nt = 0; nt < 2; nt++)
                acc[mt][nt] = __builtin_amdgcn_mfma_f32_16x16x32_bf16(
                    a[mt], bb[nt], acc[mt][nt], 0, 0, 0);
    }

#pragma unroll
    for (int mt = 0; mt < 2; mt++)
#pragma unroll
        for (int nt = 0; nt < 2; nt++)
#pragma unroll
            for (int r = 0; r < 4; r++) {
                int tok = m0 + mb + mt * 16 + qd * 4 + r;
                int n = n0g + nb + nt * 16 + c;
                outp[(size_t)tok * 256 + n] = acc[mt][nt][r] + bias[n];
            }
}

// ---------------------------------------------------------------------------
extern "C" void kernel_launch(void* const* d_in, const int* in_sizes, int n_in,
                              void* d_out, int out_size, void* d_ws, size_t ws_size,
                              hipStream_t stream) {
    const float* values       = (const float*)d_in[0];  // [1,8,512,256]
    const float* metadata     = (const float*)d_in[1];  // [1,8,512,64]
    const float* w_meta_outer = (const float*)d_in[2];  // [64,512]
    const float* w_qkv        = (const float*)d_in[3];  // [256,768]
    const float* w_meta_inner = (const float*)d_in[4];  // [64,512]
    const float* w_out        = (const float*)d_in[5];  // [256,256]
    const float* b_out        = (const float*)d_in[6];  // [256]
    float* out = (float*)d_out;

    char* ws = (char*)d_ws;
    int* topidx = (int*)ws;                                    // 128 B
    float* mm_part = (float*)(ws + 256);                       // 64*64 f32 = 16 KB
    unsigned short* WqkvT  = (unsigned short*)(ws + 20480);    // 768*256 bf16
    unsigned short* WmetaT = WqkvT + (size_t)768 * 256;        // 512*64
    unsigned short* WoutT  = WmetaT + (size_t)512 * 64;        // 256*256
    unsigned short* Qc     = WoutT + (size_t)256 * 256;        // 4096*512
    unsigned short* Kc     = Qc + (size_t)4096 * 512;          // 4096*512
    unsigned short* Vt     = Kc + (size_t)4096 * 512;          // 8*8*32*512
    unsigned short* AO     = Vt + (size_t)8 * 8 * 32 * 512;    // 4096*256

    prep<<<dim3(136), dim3(256), 0, stream>>>(
        w_qkv, w_meta_inner, w_out, metadata, WqkvT, WmetaT, WoutT, mm_part);
    fused1<<<dim3(1281), dim3(256), 0, stream>>>(
        values, metadata, WqkvT, WmetaT, mm_part, w_meta_outer, Qc, Kc, Vt, topidx);
    attn_mfma<<<dim3(8, 8, 8), dim3(256), 0, stream>>>(topidx, Qc, Kc, Vt, AO);
    gemm_out<<<dim3(64, 4), dim3(256), 0, stream>>>(AO, WoutT, b_out, out);
}